// Round 12
// baseline (1715.337 us; speedup 1.0000x reference)
//
#include <hip/hip_runtime.h>
#include <stdint.h>

typedef unsigned short u16;
typedef __attribute__((ext_vector_type(4))) float f32x4;
typedef __attribute__((ext_vector_type(8))) __bf16 bf16x8;
typedef __attribute__((ext_vector_type(8))) u16 u16x8;
typedef __attribute__((ext_vector_type(4))) u16 u16x4;

#define AS1 __attribute__((address_space(1)))
#define AS3 __attribute__((address_space(3)))

__device__ __forceinline__ void gload16(const void* g, void* l) {
  __builtin_amdgcn_global_load_lds((const AS1 void*)g, (AS3 void*)l, 16, 0, 0);
}

__device__ __forceinline__ float bf2f(u16 u) {
  union { uint32_t i; float f; } v; v.i = ((uint32_t)u) << 16; return v.f;
}
__device__ __forceinline__ u16 f2bf(float f) {  // RTNE
  uint32_t x = __builtin_bit_cast(uint32_t, f);
  x += 0x7fffu + ((x >> 16) & 1u);
  return (u16)(x >> 16);
}
__device__ __forceinline__ float phi_f(float x) { return x > 0.f ? x + 1.f : __expf(x); }

__device__ __forceinline__ f32x4 mfma16(bf16x8 a, bf16x8 b, f32x4 c) {
  return __builtin_amdgcn_mfma_f32_16x16x32_bf16(a, b, c, 0, 0, 0);
}

__device__ __forceinline__ int permrow(int r) {
  return (r & ~63) | (((r & 3) << 4) + ((r & 63) >> 2));
}

// ---------------- workspace layout (bytes) — total 249,102,336 ----------------
#define OFF_WQT  0ULL
#define OFF_WKT  (OFF_WQT + 524288ULL)
#define OFF_WVT  (OFF_WKT + 524288ULL)
#define OFF_WOT  (OFF_WVT + 524288ULL)
#define OFF_PQ   (OFF_WOT + 8388608ULL)
#define OFF_PKT  (OFF_PQ  + 67108864ULL)
#define OFF_VT   (OFF_PKT + 67108864ULL)
#define OFF_KVP  (OFF_VT  + 67108864ULL)
#define OFF_KVT  (OFF_KVP + 33554432ULL)
#define OFF_KSUM (OFF_KVT + 4194304ULL)
#define OFF_CTX  OFF_PKT
#define WS_NEED  (OFF_KSUM + 65536ULL)

// ------------- batched square transpose + cvt + 64-group row permute ----------
__global__ __launch_bounds__(256) void mla_transpose_cvt(const float* __restrict__ src,
                                                         u16* __restrict__ dst, int n) {
  __shared__ u16 tile[32][33];
  const int b = blockIdx.z;
  const float* s = src + (size_t)b * n * n;
  u16* d = dst + (size_t)b * n * n;
  const int x = blockIdx.x * 32 + threadIdx.x;
  const int y0 = blockIdx.y * 32 + threadIdx.y;
  #pragma unroll
  for (int i = 0; i < 32; i += 8)
    tile[threadIdx.y + i][threadIdx.x] = f2bf(s[(size_t)(y0 + i) * n + x]);
  __syncthreads();
  const int x2 = blockIdx.y * 32 + threadIdx.x;
  const int y2 = blockIdx.x * 32 + threadIdx.y;
  #pragma unroll
  for (int i = 0; i < 32; i += 8) {
    int pr = permrow(y2 + i);
    d[(size_t)pr * n + x2] = tile[threadIdx.x][threadIdx.y + i];
  }
}

// ---------------- K1: q/k/v projections + phi — T14 W-prefetch (r10) ---------
__global__ __launch_bounds__(256, 2) void mla_qkv(
    const float* __restrict__ X, const u16* __restrict__ WqT,
    const u16* __restrict__ WkT, const u16* __restrict__ WvT,
    u16* __restrict__ pq, u16* __restrict__ pkT, u16* __restrict__ vT) {
  __shared__ u16 ldsX[128 * 128];
  __shared__ u16 ldsW[128 * 128];
  const int t = threadIdx.x;
  const int rt = blockIdx.x, h = blockIdx.y;
  const int r0 = rt * 128;
  const int b = r0 >> 11;
  const int sl0 = r0 & 2047;
  const int bh = b * 16 + h;
  const u16* W0g = WqT + h * 16384;
  const u16* W1g = WkT + h * 16384;
  const u16* W2g = WvT + h * 16384;

  // W0 -> LDS (async), W1/W2 -> registers (plain loads, issued early)
  #pragma unroll
  for (int i = 0; i < 8; ++i)
    gload16(W0g + i * 2048 + t * 8, &ldsW[i * 2048 + t * 8]);
  u16x8 w1r[8], w2r[8];
  #pragma unroll
  for (int i = 0; i < 8; ++i) w1r[i] = *(const u16x8*)(W1g + i * 2048 + t * 8);
  #pragma unroll
  for (int i = 0; i < 8; ++i) w2r[i] = *(const u16x8*)(W2g + i * 2048 + t * 8);

  const float* Xg = X + (size_t)r0 * 2048 + h * 128;
  #pragma unroll
  for (int j = 0; j < 8; ++j) {
    int e = j * 2048 + t * 8;
    int row = e >> 7, col = e & 127;
    const float* p = Xg + (size_t)row * 2048 + col;
    f32x4 a = *(const f32x4*)p;
    f32x4 c = *(const f32x4*)(p + 4);
    u16x8 wv;
    #pragma unroll
    for (int q = 0; q < 4; ++q) { wv[q] = f2bf(a[q]); wv[4 + q] = f2bf(c[q]); }
    *(u16x8*)&ldsX[permrow(row) * 128 + col] = wv;
  }
  __syncthreads();   // X + W0 visible; w1r/w2r landed during X-convert

  const int wave = t >> 6, lane = t & 63;
  const int wm = (wave >> 1) * 64, wn = (wave & 1) * 64;
  const int lr = lane & 15, lk = (lane >> 4) * 8, r4 = (lane >> 4) * 4;
  const int rainv0 = (lr & 3) * 16 + (lr >> 2);

  for (int wsel = 0; wsel < 3; ++wsel) {
    if (wsel) {
      __syncthreads();                     // all waves done reading ldsW
      const u16x8* wsrcr = (wsel == 1) ? w1r : w2r;
      #pragma unroll
      for (int i = 0; i < 8; ++i)
        *(u16x8*)&ldsW[i * 2048 + t * 8] = wsrcr[i];
      __syncthreads();                     // new W visible (reg->LDS)
    }
    f32x4 acc[4][4];
    #pragma unroll
    for (int mb = 0; mb < 4; ++mb)
      #pragma unroll
      for (int nb = 0; nb < 4; ++nb) acc[mb][nb] = (f32x4)0.f;

    if (wsel == 0) {
      #pragma unroll
      for (int ks = 0; ks < 4; ++ks) {
        bf16x8 af[4], bb[4];
        #pragma unroll
        for (int mb = 0; mb < 4; ++mb)
          af[mb] = *(const bf16x8*)&ldsX[(wm + rainv0 + mb * 4) * 128 + ks * 32 + lk];
        #pragma unroll
        for (int nb = 0; nb < 4; ++nb)
          bb[nb] = *(const bf16x8*)&ldsW[(wn + nb * 16 + lr) * 128 + ks * 32 + lk];
        #pragma unroll
        for (int mb = 0; mb < 4; ++mb)
          #pragma unroll
          for (int nb = 0; nb < 4; ++nb)
            acc[mb][nb] = mfma16(af[mb], bb[nb], acc[mb][nb]);
      }
      u16* outq = pq + (size_t)bh * 262144 + (size_t)sl0 * 128;
      #pragma unroll
      for (int mb = 0; mb < 4; ++mb)
        #pragma unroll
        for (int j = 0; j < 4; ++j) {
          int srow = wm + mb * 16 + r4 + j;
          u16x4 o;
          #pragma unroll
          for (int nb = 0; nb < 4; ++nb) o[nb] = f2bf(phi_f(acc[mb][nb][j]));
          *(u16x4*)&outq[srow * 128 + wn + 4 * lr] = o;
        }
    } else {
      #pragma unroll
      for (int ks = 0; ks < 4; ++ks) {
        bf16x8 af[4], bb[4];
        #pragma unroll
        for (int mb = 0; mb < 4; ++mb)
          af[mb] = *(const bf16x8*)&ldsW[(wm + rainv0 + mb * 4) * 128 + ks * 32 + lk];
        #pragma unroll
        for (int nb = 0; nb < 4; ++nb)
          bb[nb] = *(const bf16x8*)&ldsX[(wn + nb * 16 + lr) * 128 + ks * 32 + lk];
        #pragma unroll
        for (int mb = 0; mb < 4; ++mb)
          #pragma unroll
          for (int nb = 0; nb < 4; ++nb)
            acc[mb][nb] = mfma16(af[mb], bb[nb], acc[mb][nb]);
      }
      u16* outT = (wsel == 1 ? pkT : vT) + (size_t)bh * 262144 + sl0;
      #pragma unroll
      for (int mb = 0; mb < 4; ++mb)
        #pragma unroll
        for (int j = 0; j < 4; ++j) {
          int drow = wm + mb * 16 + r4 + j;
          u16x4 o;
          #pragma unroll
          for (int nb = 0; nb < 4; ++nb) {
            float v0 = acc[mb][nb][j];
            if (wsel == 1) v0 = phi_f(v0);
            o[nb] = f2bf(v0);
          }
          *(u16x4*)&outT[(size_t)drow * 2048 + wn + 4 * lr] = o;
        }
    }
  }
}

// ---------------- K2: kv^T partials — ring-4 pipelined (r7, verified) --------
__global__ __launch_bounds__(256) void mla_kv(
    const u16* __restrict__ pkT, const u16* __restrict__ vT, float* __restrict__ kvp) {
  __shared__ u16 ldsA[4 * 4096];
  __shared__ u16 ldsB[4 * 4096];
  const int t = threadIdx.x;
  const int bh = blockIdx.x, part = blockIdx.y;
  const int s0 = part * 512;
  const u16* Ag = pkT + (size_t)bh * 262144;
  const u16* Bg = vT + (size_t)bh * 262144;

  const int o0 = t * 16;
  const int row0 = o0 >> 6;
  const int c0 = ((((o0 >> 4) & 3) ^ ((row0 >> 1) & 3)) * 8);

  const int wave = t >> 6, lane = t & 63;
  const int wm = (wave >> 1) * 64, wn = (wave & 1) * 64;
  const int lr = lane & 15, hi = lane >> 4, r4 = (lane >> 4) * 4;

  char* lA = (char*)ldsA;
  char* lB = (char*)ldsB;

#define KV_STAGE(u, slotb) do { const int _sc = s0 + (u) * 32 + c0; \
    gload16(Ag + (size_t)row0 * 2048 + _sc, lA + (slotb) + o0); \
    gload16(Ag + (size_t)(row0 + 64) * 2048 + _sc, lA + (slotb) + o0 + 4096); \
    gload16(Bg + (size_t)row0 * 2048 + _sc, lB + (slotb) + o0); \
    gload16(Bg + (size_t)(row0 + 64) * 2048 + _sc, lB + (slotb) + o0 + 4096); } while (0)

  auto rdA = [&](int slotb, int r) -> bf16x8 {
    int pp = (r << 6) + (hi << 4);
    pp ^= ((r >> 1) & 3) << 4;
    return *(const bf16x8*)(lA + slotb + pp);
  };
  auto rdB = [&](int slotb, int r) -> bf16x8 {
    int pp = (r << 6) + (hi << 4);
    pp ^= ((r >> 1) & 3) << 4;
    return *(const bf16x8*)(lB + slotb + pp);
  };

  f32x4 acc[4][4];
  #pragma unroll
  for (int mb = 0; mb < 4; ++mb)
    #pragma unroll
    for (int nb = 0; nb < 4; ++nb) acc[mb][nb] = (f32x4)0.f;

  KV_STAGE(0, 0); KV_STAGE(1, 8192); KV_STAGE(2, 16384);
  asm volatile("s_waitcnt vmcnt(8)" ::: "memory");
  __builtin_amdgcn_s_barrier();

  bf16x8 af[4], bb[4];
  for (int u = 0; u < 13; ++u) {
    const int sb = (u & 3) * 8192;
    #pragma unroll
    for (int mb = 0; mb < 4; ++mb) af[mb] = rdB(sb, wm + mb * 16 + lr);  // v: m=e
    #pragma unroll
    for (int nb = 0; nb < 4; ++nb) bb[nb] = rdA(sb, wn + nb * 16 + lr);  // pk: n=d
    KV_STAGE(u + 3, ((u + 3) & 3) * 8192);
    __builtin_amdgcn_sched_barrier(0);
    __builtin_amdgcn_s_barrier();
    __builtin_amdgcn_s_setprio(1);
    #pragma unroll
    for (int mb = 0; mb < 4; ++mb)
      #pragma unroll
      for (int nb = 0; nb < 4; ++nb)
        acc[mb][nb] = mfma16(af[mb], bb[nb], acc[mb][nb]);
    __builtin_amdgcn_s_setprio(0);
    asm volatile("s_waitcnt vmcnt(8)" ::: "memory");
    __builtin_amdgcn_s_barrier();
  }
  asm volatile("s_waitcnt vmcnt(0)" ::: "memory");
  __builtin_amdgcn_s_barrier();
  #pragma unroll
  for (int u = 13; u < 16; ++u) {
    const int sb = (u & 3) * 8192;
    #pragma unroll
    for (int mb = 0; mb < 4; ++mb) af[mb] = rdB(sb, wm + mb * 16 + lr);
    #pragma unroll
    for (int nb = 0; nb < 4; ++nb) bb[nb] = rdA(sb, wn + nb * 16 + lr);
    #pragma unroll
    for (int mb = 0; mb < 4; ++mb)
      #pragma unroll
      for (int nb = 0; nb < 4; ++nb)
        acc[mb][nb] = mfma16(af[mb], bb[nb], acc[mb][nb]);
  }
#undef KV_STAGE

  float* op = kvp + ((size_t)part * 128 + bh) * 16384;   // [e][d]
  #pragma unroll
  for (int mb = 0; mb < 4; ++mb)
    #pragma unroll
    for (int nb = 0; nb < 4; ++nb)
      #pragma unroll
      for (int j = 0; j < 4; ++j)
        op[(wm + mb * 16 + r4 + j) * 128 + wn + nb * 16 + lr] = acc[mb][nb][j];
}

// -------- K2b+K2c merged: partial-reduce -> kv^T bf16, and ksum --------------
__global__ __launch_bounds__(256) void mla_kvred_ksum(
    const float* __restrict__ kvp, const u16* __restrict__ pkT,
    u16* __restrict__ kvT, float* __restrict__ ksum) {
  const int bid = (int)blockIdx.x;
  const int t = threadIdx.x;
  if (bid < 1024) {
    const size_t i0 = ((size_t)bid * 256 + t) * 8;
    f32x4 lo = (f32x4)0.f, hi = (f32x4)0.f;
    #pragma unroll
    for (int p = 0; p < 4; ++p) {
      const float* src = kvp + (size_t)p * 2097152 + i0;
      lo += *(const f32x4*)src;
      hi += *(const f32x4*)(src + 4);
    }
    u16x8 o;
    #pragma unroll
    for (int j = 0; j < 4; ++j) { o[j] = f2bf(lo[j]); o[4 + j] = f2bf(hi[j]); }
    *(u16x8*)(kvT + i0) = o;
  } else {
    const int lane = t & 63, wave = t >> 6;
    const int gw = (bid - 1024) * 4 + wave;
    const u16* row = pkT + (size_t)gw * 2048;
    float s = 0.f;
    #pragma unroll
    for (int g = 0; g < 4; ++g) {
      u16x8 v = *(const u16x8*)&row[g * 512 + lane * 8];
      #pragma unroll
      for (int j = 0; j < 8; ++j) s += bf2f(v[j]);
    }
    #pragma unroll
    for (int off = 32; off; off >>= 1) s += __shfl_down(s, off);
    if (lane == 0) ksum[gw] = s;
  }
}

// ---------------- K3: num = pq@kv, den = pq@ksum, ctx = num/(den+eps) --------
__global__ __launch_bounds__(256) void mla_ctx(
    const u16* __restrict__ pq, const u16* __restrict__ kvT,
    const float* __restrict__ ksum, u16* __restrict__ ctx) {
  __shared__ u16 ldsA[128 * 128];
  __shared__ float ksl[128];
  __shared__ float dls[128];
  const int t = threadIdx.x;
  const int st = blockIdx.x, bh = blockIdx.y;
  const int sl0 = st * 128;
  const u16* Ag = pq + (size_t)bh * 262144 + (size_t)sl0 * 128;
  const u16* Bg = kvT + (size_t)bh * 16384;
  #pragma unroll
  for (int i = 0; i < 8; ++i)
    gload16(Ag + i * 2048 + t * 8, &ldsA[i * 2048 + t * 8]);
  if (t < 128) ksl[t] = ksum[bh * 128 + t];
  __syncthreads();
  const int wave = t >> 6, lane = t & 63;
  const int wm = (wave >> 1) * 64, wn = (wave & 1) * 64;
  const int lr = lane & 15, lk = (lane >> 4) * 8, r4 = (lane >> 4) * 4;
  f32x4 acc[4][4];
  #pragma unroll
  for (int mb = 0; mb < 4; ++mb)
    #pragma unroll
    for (int nb = 0; nb < 4; ++nb) acc[mb][nb] = (f32x4)0.f;
  #pragma unroll
  for (int ks = 0; ks < 4; ++ks) {
    bf16x8 af[4], bb[4];
    #pragma unroll
    for (int mb = 0; mb < 4; ++mb)
      af[mb] = *(const bf16x8*)&ldsA[(wm + mb * 16 + lr) * 128 + ks * 32 + lk];
    #pragma unroll
    for (int nb = 0; nb < 4; ++nb)
      bb[nb] = *(const bf16x8*)(Bg + (wn + 4 * lr + nb) * 128 + ks * 32 + lk);
    #pragma unroll
    for (int mb = 0; mb < 4; ++mb)
      #pragma unroll
      for (int nb = 0; nb < 4; ++nb)
        acc[mb][nb] = mfma16(af[mb], bb[nb], acc[mb][nb]);
  }
  if (t < 128) {
    float s = 0.f;
    #pragma unroll
    for (int g = 0; g < 16; ++g) {
      int blk = (g + t) & 15;
      u16x8 v = *(const u16x8*)&ldsA[t * 128 + blk * 8];
      #pragma unroll
      for (int j = 0; j < 8; ++j) s += bf2f(v[j]) * ksl[blk * 8 + j];
    }
    dls[t] = s + 1e-6f;
  }
  __syncthreads();
  const int b = bh >> 4, h = bh & 15;
  u16* oc = ctx + ((size_t)b * 2048 + sl0) * 2048 + h * 128;
  #pragma unroll
  for (int mb = 0; mb < 4; ++mb)
    #pragma unroll
    for (int j = 0; j < 4; ++j) {
      int srow = wm + mb * 16 + r4 + j;
      u16x4 o;
      #pragma unroll
      for (int nb = 0; nb < 4; ++nb) o[nb] = f2bf(acc[mb][nb][j] / dls[srow]);
      *(u16x4*)&oc[(size_t)srow * 2048 + wn + 4 * lr] = o;
    }
}

// ---------------- K4: out = ctx @ Wo + bo — ring-2, 2 blocks/CU --------------
// 64 KB LDS (2 slots/operand) -> 2 blocks resident per CU: sibling block's
// MFMA covers this block's vmcnt/barrier stalls (m114 overlap). Per substep:
// reads(u) slot u&1 -> 32 MFMA -> vmcnt(0) [u+1 resident] -> barrier ->
// STAGE(u+2 into slot u&1) (safe: all waves' reads of that slot completed).
__global__ __launch_bounds__(512, 4) void mla_out8(
    const u16* __restrict__ ctx, const u16* __restrict__ WoT,
    const float* __restrict__ bo, float* __restrict__ out) {
  __shared__ u16 ldsA[2 * 8192];
  __shared__ u16 ldsB[2 * 8192];
  const int t = threadIdx.x;
  const int bid = (int)blockIdx.x;
  const int swz = (bid & 7) * 64 + (bid >> 3);
  const int mt = swz >> 3, nt = swz & 7;
  const u16* Ag = ctx + (size_t)mt * 256 * 2048;
  const u16* Bg = WoT + (size_t)nt * 256 * 2048;

  const int o0 = t * 16;
  const int row0 = o0 >> 6;
  const int c0 = ((((o0 >> 4) & 3) ^ ((row0 >> 1) & 3)) * 8);

  const int w = t >> 6, lane = t & 63;
  const int wrow = (w >> 2) * 128;
  const int wcol = (w & 3) * 64;
  const int lr = lane & 15, hi = lane >> 4, r4 = (lane >> 4) * 4;

  f32x4 bocache = *(const f32x4*)&bo[nt * 256 + wcol + 4 * lr];

  char* lA = (char*)ldsA;
  char* lB = (char*)ldsB;

#define STAGE_AB(u, sl) do { \
    gload16(Ag + (size_t)row0 * 2048 + (u) * 32 + c0, lA + (sl) + o0); \
    gload16(Ag + (size_t)(row0 + 128) * 2048 + (u) * 32 + c0, lA + (sl) + o0 + 8192); \
    gload16(Bg + (size_t)row0 * 2048 + (u) * 32 + c0, lB + (sl) + o0); \
    gload16(Bg + (size_t)(row0 + 128) * 2048 + (u) * 32 + c0, lB + (sl) + o0 + 8192); } while (0)

  auto rdA = [&](int slotb, int r) -> bf16x8 {
    int p = (r << 6) + (hi << 4);
    p ^= ((r >> 1) & 3) << 4;
    return *(const bf16x8*)(lA + slotb + p);
  };
  auto rdB = [&](int slotb, int r) -> bf16x8 {
    int p = (r << 6) + (hi << 4);
    p ^= ((r >> 1) & 3) << 4;
    return *(const bf16x8*)(lB + slotb + p);
  };

  f32x4 acc0[4][4], acc1[4][4];
  #pragma unroll
  for (int mb = 0; mb < 4; ++mb)
    #pragma unroll
    for (int nb = 0; nb < 4; ++nb) { acc0[mb][nb] = (f32x4)0.f; acc1[mb][nb] = (f32x4)0.f; }

  bf16x8 af[8], bb[4];

#define READS(sb) do { \
    _Pragma("unroll") \
    for (int nf = 0; nf < 4; ++nf) bb[nf] = rdB((sb), wcol + nf * 16 + lr); \
    _Pragma("unroll") \
    for (int mf = 0; mf < 8; ++mf) af[mf] = rdA((sb), wrow + mf * 16 + lr); } while (0)

#define CLUSTER() do { \
    __builtin_amdgcn_s_setprio(1); \
    _Pragma("unroll") \
    for (int mb = 0; mb < 4; ++mb) { \
      _Pragma("unroll") \
      for (int nb = 0; nb < 4; ++nb) acc0[mb][nb] = mfma16(af[mb], bb[nb], acc0[mb][nb]); } \
    _Pragma("unroll") \
    for (int mb = 0; mb < 4; ++mb) { \
      _Pragma("unroll") \
      for (int nb = 0; nb < 4; ++nb) acc1[mb][nb] = mfma16(af[4 + mb], bb[nb], acc1[mb][nb]); } \
    __builtin_amdgcn_s_setprio(0); } while (0)

  // prologue: stage 0 -> slot0, 1 -> slot1; wait slot0 resident
  STAGE_AB(0, 0); STAGE_AB(1, 16384);
  asm volatile("s_waitcnt vmcnt(4)" ::: "memory");
  __builtin_amdgcn_s_barrier();

  for (int it = 0; it < 31; ++it) {
    const int u0 = it * 2;
    // u0 (even, slot0)
    READS(0);
    CLUSTER();
    asm volatile("s_waitcnt vmcnt(0)" ::: "memory");   // u0+1 resident
    __builtin_amdgcn_s_barrier();                      // all done reading slot0
    STAGE_AB(u0 + 2, 0);                               // overwrite slot0
    // u0+1 (odd, slot1)
    READS(16384);
    CLUSTER();
    asm volatile("s_waitcnt vmcnt(0)" ::: "memory");   // u0+2 resident
    __builtin_amdgcn_s_barrier();                      // all done reading slot1
    STAGE_AB(u0 + 3, 16384);                           // overwrite slot1
  }
  // u=62 (slot0): 63 already staged; drain it, no more staging
  READS(0);
  CLUSTER();
  asm volatile("s_waitcnt vmcnt(0)" ::: "memory");
  __builtin_amdgcn_s_barrier();
  // u=63 (slot1)
  READS(16384);
  CLUSTER();
#undef STAGE_AB
#undef READS
#undef CLUSTER

  const size_t obase = (size_t)(mt * 256 + wrow) * 2048 + nt * 256 + wcol + 4 * lr;
  #pragma unroll
  for (int mb = 0; mb < 4; ++mb)
    #pragma unroll
    for (int j = 0; j < 4; ++j) {
      f32x4 v0, v1;
      #pragma unroll
      for (int nb = 0; nb < 4; ++nb) {
        v0[nb] = acc0[mb][nb][j] + bocache[nb];
        v1[nb] = acc1[mb][nb][j] + bocache[nb];
      }
      *(f32x4*)&out[obase + (size_t)(mb * 16 + r4 + j) * 2048] = v0;
      *(f32x4*)&out[obase + (size_t)(64 + mb * 16 + r4 + j) * 2048] = v1;
    }
}

extern "C" void kernel_launch(void* const* d_in, const int* in_sizes, int n_in,
                              void* d_out, int out_size, void* d_ws, size_t ws_size,
                              hipStream_t stream) {
  (void)in_sizes; (void)n_in; (void)out_size;
  const float* X  = (const float*)d_in[0];
  const float* Wq = (const float*)d_in[1];
  const float* Wk = (const float*)d_in[2];
  const float* Wv = (const float*)d_in[3];
  const float* Wo = (const float*)d_in[4];
  const float* bo = (const float*)d_in[5];
  float* out = (float*)d_out;
  char* ws = (char*)d_ws;
  if (ws_size < WS_NEED) return;

  u16*   wqT  = (u16*)(ws + OFF_WQT);
  u16*   wkT  = (u16*)(ws + OFF_WKT);
  u16*   wvT  = (u16*)(ws + OFF_WVT);
  u16*   woT  = (u16*)(ws + OFF_WOT);
  u16*   pq   = (u16*)(ws + OFF_PQ);
  u16*   pkT  = (u16*)(ws + OFF_PKT);
  u16*   vT   = (u16*)(ws + OFF_VT);
  float* kvp  = (float*)(ws + OFF_KVP);
  u16*   kvT  = (u16*)(ws + OFF_KVT);
  float* ksum = (float*)(ws + OFF_KSUM);
  u16*   ctx  = (u16*)(ws + OFF_CTX);

  dim3 tb(32, 8);
  mla_transpose_cvt<<<dim3(4, 4, 16), tb, 0, stream>>>(Wq, wqT, 128);
  mla_transpose_cvt<<<dim3(4, 4, 16), tb, 0, stream>>>(Wk, wkT, 128);
  mla_transpose_cvt<<<dim3(4, 4, 16), tb, 0, stream>>>(Wv, wvT, 128);
  mla_transpose_cvt<<<dim3(64, 64, 1), tb, 0, stream>>>(Wo, woT, 2048);
  mla_qkv<<<dim3(128, 16), 256, 0, stream>>>(X, wqT, wkT, wvT, pq, pkT, vT);
  mla_kv<<<dim3(128, 4), 256, 0, stream>>>(pkT, vT, kvp);
  mla_kvred_ksum<<<5120, 256, 0, stream>>>(kvp, pkT, kvT, ksum);
  mla_ctx<<<dim3(16, 128), 256, 0, stream>>>(pq, kvT, ksum, ctx);
  mla_out8<<<512, 512, 0, stream>>>(ctx, woT, bo, out);
}

// Round 13
// 356.515 us; speedup vs baseline: 4.8114x; 4.8114x over previous
//
#include <hip/hip_runtime.h>
#include <stdint.h>

typedef unsigned short u16;
typedef __attribute__((ext_vector_type(4))) float f32x4;
typedef __attribute__((ext_vector_type(8))) __bf16 bf16x8;
typedef __attribute__((ext_vector_type(8))) u16 u16x8;
typedef __attribute__((ext_vector_type(4))) u16 u16x4;

#define AS1 __attribute__((address_space(1)))
#define AS3 __attribute__((address_space(3)))

__device__ __forceinline__ void gload16(const void* g, void* l) {
  __builtin_amdgcn_global_load_lds((const AS1 void*)g, (AS3 void*)l, 16, 0, 0);
}

__device__ __forceinline__ float bf2f(u16 u) {
  union { uint32_t i; float f; } v; v.i = ((uint32_t)u) << 16; return v.f;
}
__device__ __forceinline__ u16 f2bf(float f) {  // RTNE
  uint32_t x = __builtin_bit_cast(uint32_t, f);
  x += 0x7fffu + ((x >> 16) & 1u);
  return (u16)(x >> 16);
}
__device__ __forceinline__ float phi_f(float x) { return x > 0.f ? x + 1.f : __expf(x); }

__device__ __forceinline__ f32x4 mfma16(bf16x8 a, bf16x8 b, f32x4 c) {
  return __builtin_amdgcn_mfma_f32_16x16x32_bf16(a, b, c, 0, 0, 0);
}

__device__ __forceinline__ int permrow(int r) {
  return (r & ~63) | (((r & 3) << 4) + ((r & 63) >> 2));
}

// ---------------- workspace layout (bytes) — total 249,102,336 ----------------
#define OFF_WQT  0ULL
#define OFF_WKT  (OFF_WQT + 524288ULL)
#define OFF_WVT  (OFF_WKT + 524288ULL)
#define OFF_WOT  (OFF_WVT + 524288ULL)
#define OFF_PQ   (OFF_WOT + 8388608ULL)
#define OFF_PKT  (OFF_PQ  + 67108864ULL)
#define OFF_VT   (OFF_PKT + 67108864ULL)
#define OFF_KVP  (OFF_VT  + 67108864ULL)
#define OFF_KVT  (OFF_KVP + 33554432ULL)
#define OFF_KSUM (OFF_KVT + 4194304ULL)
#define OFF_CTX  OFF_PKT
#define WS_NEED  (OFF_KSUM + 65536ULL)

// ------------- batched square transpose + cvt + 64-group row permute ----------
__global__ __launch_bounds__(256) void mla_transpose_cvt(const float* __restrict__ src,
                                                         u16* __restrict__ dst, int n) {
  __shared__ u16 tile[32][33];
  const int b = blockIdx.z;
  const float* s = src + (size_t)b * n * n;
  u16* d = dst + (size_t)b * n * n;
  const int x = blockIdx.x * 32 + threadIdx.x;
  const int y0 = blockIdx.y * 32 + threadIdx.y;
  #pragma unroll
  for (int i = 0; i < 32; i += 8)
    tile[threadIdx.y + i][threadIdx.x] = f2bf(s[(size_t)(y0 + i) * n + x]);
  __syncthreads();
  const int x2 = blockIdx.y * 32 + threadIdx.x;
  const int y2 = blockIdx.x * 32 + threadIdx.y;
  #pragma unroll
  for (int i = 0; i < 32; i += 8) {
    int pr = permrow(y2 + i);
    d[(size_t)pr * n + x2] = tile[threadIdx.x][threadIdx.y + i];
  }
}

// ---------------- K1: q/k/v projections + phi — T14 W-prefetch (r10) ---------
__global__ __launch_bounds__(256, 2) void mla_qkv(
    const float* __restrict__ X, const u16* __restrict__ WqT,
    const u16* __restrict__ WkT, const u16* __restrict__ WvT,
    u16* __restrict__ pq, u16* __restrict__ pkT, u16* __restrict__ vT) {
  __shared__ u16 ldsX[128 * 128];
  __shared__ u16 ldsW[128 * 128];
  const int t = threadIdx.x;
  const int rt = blockIdx.x, h = blockIdx.y;
  const int r0 = rt * 128;
  const int b = r0 >> 11;
  const int sl0 = r0 & 2047;
  const int bh = b * 16 + h;
  const u16* W0g = WqT + h * 16384;
  const u16* W1g = WkT + h * 16384;
  const u16* W2g = WvT + h * 16384;

  // W0 -> LDS (async), W1/W2 -> registers (plain loads, issued early)
  #pragma unroll
  for (int i = 0; i < 8; ++i)
    gload16(W0g + i * 2048 + t * 8, &ldsW[i * 2048 + t * 8]);
  u16x8 w1r[8], w2r[8];
  #pragma unroll
  for (int i = 0; i < 8; ++i) w1r[i] = *(const u16x8*)(W1g + i * 2048 + t * 8);
  #pragma unroll
  for (int i = 0; i < 8; ++i) w2r[i] = *(const u16x8*)(W2g + i * 2048 + t * 8);

  const float* Xg = X + (size_t)r0 * 2048 + h * 128;
  #pragma unroll
  for (int j = 0; j < 8; ++j) {
    int e = j * 2048 + t * 8;
    int row = e >> 7, col = e & 127;
    const float* p = Xg + (size_t)row * 2048 + col;
    f32x4 a = *(const f32x4*)p;
    f32x4 c = *(const f32x4*)(p + 4);
    u16x8 wv;
    #pragma unroll
    for (int q = 0; q < 4; ++q) { wv[q] = f2bf(a[q]); wv[4 + q] = f2bf(c[q]); }
    *(u16x8*)&ldsX[permrow(row) * 128 + col] = wv;
  }
  __syncthreads();   // X + W0 visible; w1r/w2r landed during X-convert

  const int wave = t >> 6, lane = t & 63;
  const int wm = (wave >> 1) * 64, wn = (wave & 1) * 64;
  const int lr = lane & 15, lk = (lane >> 4) * 8, r4 = (lane >> 4) * 4;
  const int rainv0 = (lr & 3) * 16 + (lr >> 2);

  for (int wsel = 0; wsel < 3; ++wsel) {
    if (wsel) {
      __syncthreads();                     // all waves done reading ldsW
      const u16x8* wsrcr = (wsel == 1) ? w1r : w2r;
      #pragma unroll
      for (int i = 0; i < 8; ++i)
        *(u16x8*)&ldsW[i * 2048 + t * 8] = wsrcr[i];
      __syncthreads();                     // new W visible (reg->LDS)
    }
    f32x4 acc[4][4];
    #pragma unroll
    for (int mb = 0; mb < 4; ++mb)
      #pragma unroll
      for (int nb = 0; nb < 4; ++nb) acc[mb][nb] = (f32x4)0.f;

    if (wsel == 0) {
      #pragma unroll
      for (int ks = 0; ks < 4; ++ks) {
        bf16x8 af[4], bb[4];
        #pragma unroll
        for (int mb = 0; mb < 4; ++mb)
          af[mb] = *(const bf16x8*)&ldsX[(wm + rainv0 + mb * 4) * 128 + ks * 32 + lk];
        #pragma unroll
        for (int nb = 0; nb < 4; ++nb)
          bb[nb] = *(const bf16x8*)&ldsW[(wn + nb * 16 + lr) * 128 + ks * 32 + lk];
        #pragma unroll
        for (int mb = 0; mb < 4; ++mb)
          #pragma unroll
          for (int nb = 0; nb < 4; ++nb)
            acc[mb][nb] = mfma16(af[mb], bb[nb], acc[mb][nb]);
      }
      u16* outq = pq + (size_t)bh * 262144 + (size_t)sl0 * 128;
      #pragma unroll
      for (int mb = 0; mb < 4; ++mb)
        #pragma unroll
        for (int j = 0; j < 4; ++j) {
          int srow = wm + mb * 16 + r4 + j;
          u16x4 o;
          #pragma unroll
          for (int nb = 0; nb < 4; ++nb) o[nb] = f2bf(phi_f(acc[mb][nb][j]));
          *(u16x4*)&outq[srow * 128 + wn + 4 * lr] = o;
        }
    } else {
      #pragma unroll
      for (int ks = 0; ks < 4; ++ks) {
        bf16x8 af[4], bb[4];
        #pragma unroll
        for (int mb = 0; mb < 4; ++mb)
          af[mb] = *(const bf16x8*)&ldsW[(wm + rainv0 + mb * 4) * 128 + ks * 32 + lk];
        #pragma unroll
        for (int nb = 0; nb < 4; ++nb)
          bb[nb] = *(const bf16x8*)&ldsX[(wn + nb * 16 + lr) * 128 + ks * 32 + lk];
        #pragma unroll
        for (int mb = 0; mb < 4; ++mb)
          #pragma unroll
          for (int nb = 0; nb < 4; ++nb)
            acc[mb][nb] = mfma16(af[mb], bb[nb], acc[mb][nb]);
      }
      u16* outT = (wsel == 1 ? pkT : vT) + (size_t)bh * 262144 + sl0;
      #pragma unroll
      for (int mb = 0; mb < 4; ++mb)
        #pragma unroll
        for (int j = 0; j < 4; ++j) {
          int drow = wm + mb * 16 + r4 + j;
          u16x4 o;
          #pragma unroll
          for (int nb = 0; nb < 4; ++nb) {
            float v0 = acc[mb][nb][j];
            if (wsel == 1) v0 = phi_f(v0);
            o[nb] = f2bf(v0);
          }
          *(u16x4*)&outT[(size_t)drow * 2048 + wn + 4 * lr] = o;
        }
    }
  }
}

// ---------------- K2: kv^T partials — ring-4 pipelined (r7, verified) --------
__global__ __launch_bounds__(256) void mla_kv(
    const u16* __restrict__ pkT, const u16* __restrict__ vT, float* __restrict__ kvp) {
  __shared__ u16 ldsA[4 * 4096];
  __shared__ u16 ldsB[4 * 4096];
  const int t = threadIdx.x;
  const int bh = blockIdx.x, part = blockIdx.y;
  const int s0 = part * 512;
  const u16* Ag = pkT + (size_t)bh * 262144;
  const u16* Bg = vT + (size_t)bh * 262144;

  const int o0 = t * 16;
  const int row0 = o0 >> 6;
  const int c0 = ((((o0 >> 4) & 3) ^ ((row0 >> 1) & 3)) * 8);

  const int wave = t >> 6, lane = t & 63;
  const int wm = (wave >> 1) * 64, wn = (wave & 1) * 64;
  const int lr = lane & 15, hi = lane >> 4, r4 = (lane >> 4) * 4;

  char* lA = (char*)ldsA;
  char* lB = (char*)ldsB;

#define KV_STAGE(u, slotb) do { const int _sc = s0 + (u) * 32 + c0; \
    gload16(Ag + (size_t)row0 * 2048 + _sc, lA + (slotb) + o0); \
    gload16(Ag + (size_t)(row0 + 64) * 2048 + _sc, lA + (slotb) + o0 + 4096); \
    gload16(Bg + (size_t)row0 * 2048 + _sc, lB + (slotb) + o0); \
    gload16(Bg + (size_t)(row0 + 64) * 2048 + _sc, lB + (slotb) + o0 + 4096); } while (0)

  auto rdA = [&](int slotb, int r) -> bf16x8 {
    int pp = (r << 6) + (hi << 4);
    pp ^= ((r >> 1) & 3) << 4;
    return *(const bf16x8*)(lA + slotb + pp);
  };
  auto rdB = [&](int slotb, int r) -> bf16x8 {
    int pp = (r << 6) + (hi << 4);
    pp ^= ((r >> 1) & 3) << 4;
    return *(const bf16x8*)(lB + slotb + pp);
  };

  f32x4 acc[4][4];
  #pragma unroll
  for (int mb = 0; mb < 4; ++mb)
    #pragma unroll
    for (int nb = 0; nb < 4; ++nb) acc[mb][nb] = (f32x4)0.f;

  KV_STAGE(0, 0); KV_STAGE(1, 8192); KV_STAGE(2, 16384);
  asm volatile("s_waitcnt vmcnt(8)" ::: "memory");
  __builtin_amdgcn_s_barrier();

  bf16x8 af[4], bb[4];
  for (int u = 0; u < 13; ++u) {
    const int sb = (u & 3) * 8192;
    #pragma unroll
    for (int mb = 0; mb < 4; ++mb) af[mb] = rdB(sb, wm + mb * 16 + lr);  // v: m=e
    #pragma unroll
    for (int nb = 0; nb < 4; ++nb) bb[nb] = rdA(sb, wn + nb * 16 + lr);  // pk: n=d
    KV_STAGE(u + 3, ((u + 3) & 3) * 8192);
    __builtin_amdgcn_sched_barrier(0);
    __builtin_amdgcn_s_barrier();
    __builtin_amdgcn_s_setprio(1);
    #pragma unroll
    for (int mb = 0; mb < 4; ++mb)
      #pragma unroll
      for (int nb = 0; nb < 4; ++nb)
        acc[mb][nb] = mfma16(af[mb], bb[nb], acc[mb][nb]);
    __builtin_amdgcn_s_setprio(0);
    asm volatile("s_waitcnt vmcnt(8)" ::: "memory");
    __builtin_amdgcn_s_barrier();
  }
  asm volatile("s_waitcnt vmcnt(0)" ::: "memory");
  __builtin_amdgcn_s_barrier();
  #pragma unroll
  for (int u = 13; u < 16; ++u) {
    const int sb = (u & 3) * 8192;
    #pragma unroll
    for (int mb = 0; mb < 4; ++mb) af[mb] = rdB(sb, wm + mb * 16 + lr);
    #pragma unroll
    for (int nb = 0; nb < 4; ++nb) bb[nb] = rdA(sb, wn + nb * 16 + lr);
    #pragma unroll
    for (int mb = 0; mb < 4; ++mb)
      #pragma unroll
      for (int nb = 0; nb < 4; ++nb)
        acc[mb][nb] = mfma16(af[mb], bb[nb], acc[mb][nb]);
  }
#undef KV_STAGE

  float* op = kvp + ((size_t)part * 128 + bh) * 16384;   // [e][d]
  #pragma unroll
  for (int mb = 0; mb < 4; ++mb)
    #pragma unroll
    for (int nb = 0; nb < 4; ++nb)
      #pragma unroll
      for (int j = 0; j < 4; ++j)
        op[(wm + mb * 16 + r4 + j) * 128 + wn + nb * 16 + lr] = acc[mb][nb][j];
}

// -------- K2b+K2c merged: partial-reduce -> kv^T bf16, and ksum --------------
__global__ __launch_bounds__(256) void mla_kvred_ksum(
    const float* __restrict__ kvp, const u16* __restrict__ pkT,
    u16* __restrict__ kvT, float* __restrict__ ksum) {
  const int bid = (int)blockIdx.x;
  const int t = threadIdx.x;
  if (bid < 1024) {
    const size_t i0 = ((size_t)bid * 256 + t) * 8;
    f32x4 lo = (f32x4)0.f, hi = (f32x4)0.f;
    #pragma unroll
    for (int p = 0; p < 4; ++p) {
      const float* src = kvp + (size_t)p * 2097152 + i0;
      lo += *(const f32x4*)src;
      hi += *(const f32x4*)(src + 4);
    }
    u16x8 o;
    #pragma unroll
    for (int j = 0; j < 4; ++j) { o[j] = f2bf(lo[j]); o[4 + j] = f2bf(hi[j]); }
    *(u16x8*)(kvT + i0) = o;
  } else {
    const int lane = t & 63, wave = t >> 6;
    const int gw = (bid - 1024) * 4 + wave;
    const u16* row = pkT + (size_t)gw * 2048;
    float s = 0.f;
    #pragma unroll
    for (int g = 0; g < 4; ++g) {
      u16x8 v = *(const u16x8*)&row[g * 512 + lane * 8];
      #pragma unroll
      for (int j = 0; j < 8; ++j) s += bf2f(v[j]);
    }
    #pragma unroll
    for (int off = 32; off; off >>= 1) s += __shfl_down(s, off);
    if (lane == 0) ksum[gw] = s;
  }
}

// ---------------- K3: num = pq@kv, den = pq@ksum, ctx = num/(den+eps) --------
__global__ __launch_bounds__(256) void mla_ctx(
    const u16* __restrict__ pq, const u16* __restrict__ kvT,
    const float* __restrict__ ksum, u16* __restrict__ ctx) {
  __shared__ u16 ldsA[128 * 128];
  __shared__ float ksl[128];
  __shared__ float dls[128];
  const int t = threadIdx.x;
  const int st = blockIdx.x, bh = blockIdx.y;
  const int sl0 = st * 128;
  const u16* Ag = pq + (size_t)bh * 262144 + (size_t)sl0 * 128;
  const u16* Bg = kvT + (size_t)bh * 16384;
  #pragma unroll
  for (int i = 0; i < 8; ++i)
    gload16(Ag + i * 2048 + t * 8, &ldsA[i * 2048 + t * 8]);
  if (t < 128) ksl[t] = ksum[bh * 128 + t];
  __syncthreads();
  const int wave = t >> 6, lane = t & 63;
  const int wm = (wave >> 1) * 64, wn = (wave & 1) * 64;
  const int lr = lane & 15, lk = (lane >> 4) * 8, r4 = (lane >> 4) * 4;
  f32x4 acc[4][4];
  #pragma unroll
  for (int mb = 0; mb < 4; ++mb)
    #pragma unroll
    for (int nb = 0; nb < 4; ++nb) acc[mb][nb] = (f32x4)0.f;
  #pragma unroll
  for (int ks = 0; ks < 4; ++ks) {
    bf16x8 af[4], bb[4];
    #pragma unroll
    for (int mb = 0; mb < 4; ++mb)
      af[mb] = *(const bf16x8*)&ldsA[(wm + mb * 16 + lr) * 128 + ks * 32 + lk];
    #pragma unroll
    for (int nb = 0; nb < 4; ++nb)
      bb[nb] = *(const bf16x8*)(Bg + (wn + 4 * lr + nb) * 128 + ks * 32 + lk);
    #pragma unroll
    for (int mb = 0; mb < 4; ++mb)
      #pragma unroll
      for (int nb = 0; nb < 4; ++nb)
        acc[mb][nb] = mfma16(af[mb], bb[nb], acc[mb][nb]);
  }
  if (t < 128) {
    float s = 0.f;
    #pragma unroll
    for (int g = 0; g < 16; ++g) {
      int blk = (g + t) & 15;
      u16x8 v = *(const u16x8*)&ldsA[t * 128 + blk * 8];
      #pragma unroll
      for (int j = 0; j < 8; ++j) s += bf2f(v[j]) * ksl[blk * 8 + j];
    }
    dls[t] = s + 1e-6f;
  }
  __syncthreads();
  const int b = bh >> 4, h = bh & 15;
  u16* oc = ctx + ((size_t)b * 2048 + sl0) * 2048 + h * 128;
  #pragma unroll
  for (int mb = 0; mb < 4; ++mb)
    #pragma unroll
    for (int j = 0; j < 4; ++j) {
      int srow = wm + mb * 16 + r4 + j;
      u16x4 o;
      #pragma unroll
      for (int nb = 0; nb < 4; ++nb) o[nb] = f2bf(acc[mb][nb][j] / dls[srow]);
      *(u16x4*)&oc[(size_t)srow * 2048 + wn + 4 * lr] = o;
    }
}

// ---------------- K4: out = ctx @ Wo + bo — merged single-phase (r9/r10) -----
__global__ __launch_bounds__(512, 2) void mla_out8(
    const u16* __restrict__ ctx, const u16* __restrict__ WoT,
    const float* __restrict__ bo, float* __restrict__ out) {
  __shared__ u16 ldsA[4 * 8192];
  __shared__ u16 ldsB[4 * 8192];
  const int t = threadIdx.x;
  const int bid = (int)blockIdx.x;
  const int swz = (bid & 7) * 64 + (bid >> 3);
  const int mt = swz >> 3, nt = swz & 7;
  const u16* Ag = ctx + (size_t)mt * 256 * 2048;
  const u16* Bg = WoT + (size_t)nt * 256 * 2048;

  const int o0 = t * 16;
  const int row0 = o0 >> 6;
  const int c0 = ((((o0 >> 4) & 3) ^ ((row0 >> 1) & 3)) * 8);

  const int w = t >> 6, lane = t & 63;
  const int wrow = (w >> 2) * 128;
  const int wcol = (w & 3) * 64;
  const int lr = lane & 15, hi = lane >> 4, r4 = (lane >> 4) * 4;

  f32x4 bocache = *(const f32x4*)&bo[nt * 256 + wcol + 4 * lr];

  char* lA = (char*)ldsA;
  char* lB = (char*)ldsB;

#define STAGE_AB(u) do { const int _sl = ((u) & 3) * 16384; \
    gload16(Ag + (size_t)row0 * 2048 + (u) * 32 + c0, lA + _sl + o0); \
    gload16(Ag + (size_t)(row0 + 128) * 2048 + (u) * 32 + c0, lA + _sl + o0 + 8192); \
    gload16(Bg + (size_t)row0 * 2048 + (u) * 32 + c0, lB + _sl + o0); \
    gload16(Bg + (size_t)(row0 + 128) * 2048 + (u) * 32 + c0, lB + _sl + o0 + 8192); } while (0)

  auto rdA = [&](int slotb, int r) -> bf16x8 {
    int p = (r << 6) + (hi << 4);
    p ^= ((r >> 1) & 3) << 4;
    return *(const bf16x8*)(lA + slotb + p);
  };
  auto rdB = [&](int slotb, int r) -> bf16x8 {
    int p = (r << 6) + (hi << 4);
    p ^= ((r >> 1) & 3) << 4;
    return *(const bf16x8*)(lB + slotb + p);
  };

  f32x4 acc0[4][4], acc1[4][4];
  #pragma unroll
  for (int mb = 0; mb < 4; ++mb)
    #pragma unroll
    for (int nb = 0; nb < 4; ++nb) { acc0[mb][nb] = (f32x4)0.f; acc1[mb][nb] = (f32x4)0.f; }

  STAGE_AB(0); STAGE_AB(1); STAGE_AB(2);
  asm volatile("s_waitcnt vmcnt(8)" ::: "memory");
  __builtin_amdgcn_s_barrier();

  bf16x8 af[8], bb[4];

  for (int u = 0; u < 61; ++u) {
    const int sb = (u & 3) * 16384;
    #pragma unroll
    for (int nb = 0; nb < 4; ++nb) bb[nb] = rdB(sb, wcol + nb * 16 + lr);
    #pragma unroll
    for (int mf = 0; mf < 8; ++mf) af[mf] = rdA(sb, wrow + mf * 16 + lr);
    STAGE_AB(u + 3);
    __builtin_amdgcn_sched_barrier(0);
    __builtin_amdgcn_s_barrier();
    __builtin_amdgcn_s_setprio(1);
    #pragma unroll
    for (int mb = 0; mb < 4; ++mb)
      #pragma unroll
      for (int nb = 0; nb < 4; ++nb)
        acc0[mb][nb] = mfma16(af[mb], bb[nb], acc0[mb][nb]);
    #pragma unroll
    for (int mb = 0; mb < 4; ++mb)
      #pragma unroll
      for (int nb = 0; nb < 4; ++nb)
        acc1[mb][nb] = mfma16(af[4 + mb], bb[nb], acc1[mb][nb]);
    __builtin_amdgcn_s_setprio(0);
    asm volatile("s_waitcnt vmcnt(8)" ::: "memory");
    __builtin_amdgcn_s_barrier();
  }

  asm volatile("s_waitcnt vmcnt(0)" ::: "memory");
  __builtin_amdgcn_s_barrier();
  #pragma unroll
  for (int u = 61; u < 64; ++u) {
    const int sb = (u & 3) * 16384;
    #pragma unroll
    for (int nb = 0; nb < 4; ++nb) bb[nb] = rdB(sb, wcol + nb * 16 + lr);
    #pragma unroll
    for (int mf = 0; mf < 8; ++mf) af[mf] = rdA(sb, wrow + mf * 16 + lr);
    #pragma unroll
    for (int mb = 0; mb < 4; ++mb)
      #pragma unroll
      for (int nb = 0; nb < 4; ++nb)
        acc0[mb][nb] = mfma16(af[mb], bb[nb], acc0[mb][nb]);
    #pragma unroll
    for (int mb = 0; mb < 4; ++mb)
      #pragma unroll
      for (int nb = 0; nb < 4; ++nb)
        acc1[mb][nb] = mfma16(af[4 + mb], bb[nb], acc1[mb][nb]);
  }
#undef STAGE_AB

  const size_t obase = (size_t)(mt * 256 + wrow) * 2048 + nt * 256 + wcol + 4 * lr;
  #pragma unroll
  for (int mb = 0; mb < 4; ++mb)
    #pragma unroll
    for (int j = 0; j < 4; ++j) {
      f32x4 v0, v1;
      #pragma unroll
      for (int nb = 0; nb < 4; ++nb) {
        v0[nb] = acc0[mb][nb][j] + bocache[nb];
        v1[nb] = acc1[mb][nb][j] + bocache[nb];
      }
      *(f32x4*)&out[obase + (size_t)(mb * 16 + r4 + j) * 2048] = v0;
      *(f32x4*)&out[obase + (size_t)(64 + mb * 16 + r4 + j) * 2048] = v1;
    }
}

extern "C" void kernel_launch(void* const* d_in, const int* in_sizes, int n_in,
                              void* d_out, int out_size, void* d_ws, size_t ws_size,
                              hipStream_t stream) {
  (void)in_sizes; (void)n_in; (void)out_size;
  const float* X  = (const float*)d_in[0];
  const float* Wq = (const float*)d_in[1];
  const float* Wk = (const float*)d_in[2];
  const float* Wv = (const float*)d_in[3];
  const float* Wo = (const float*)d_in[4];
  const float* bo = (const float*)d_in[5];
  float* out = (float*)d_out;
  char* ws = (char*)d_ws;
  if (ws_size < WS_NEED) return;

  u16*   wqT  = (u16*)(ws + OFF_WQT);
  u16*   wkT  = (u16*)(ws + OFF_WKT);
  u16*   wvT  = (u16*)(ws + OFF_WVT);
  u16*   woT  = (u16*)(ws + OFF_WOT);
  u16*   pq   = (u16*)(ws + OFF_PQ);
  u16*   pkT  = (u16*)(ws + OFF_PKT);
  u16*   vT   = (u16*)(ws + OFF_VT);
  float* kvp  = (float*)(ws + OFF_KVP);
  u16*   kvT  = (u16*)(ws + OFF_KVT);
  float* ksum = (float*)(ws + OFF_KSUM);
  u16*   ctx  = (u16*)(ws + OFF_CTX);

  dim3 tb(32, 8);
  mla_transpose_cvt<<<dim3(4, 4, 16), tb, 0, stream>>>(Wq, wqT, 128);
  mla_transpose_cvt<<<dim3(4, 4, 16), tb, 0, stream>>>(Wk, wkT, 128);
  mla_transpose_cvt<<<dim3(4, 4, 16), tb, 0, stream>>>(Wv, wvT, 128);
  mla_transpose_cvt<<<dim3(64, 64, 1), tb, 0, stream>>>(Wo, woT, 2048);
  mla_qkv<<<dim3(128, 16), 256, 0, stream>>>(X, wqT, wkT, wvT, pq, pkT, vT);
  mla_kv<<<dim3(128, 4), 256, 0, stream>>>(pkT, vT, kvp);
  mla_kvred_ksum<<<5120, 256, 0, stream>>>(kvp, pkT, kvT, ksum);
  mla_ctx<<<dim3(16, 128), 256, 0, stream>>>(pq, kvT, ksum, ctx);
  mla_out8<<<512, 512, 0, stream>>>(ctx, woT, bo, out);
}

// Round 14
// 343.909 us; speedup vs baseline: 4.9878x; 1.0367x over previous
//
#include <hip/hip_runtime.h>
#include <stdint.h>

typedef unsigned short u16;
typedef __attribute__((ext_vector_type(4))) float f32x4;
typedef __attribute__((ext_vector_type(8))) __bf16 bf16x8;
typedef __attribute__((ext_vector_type(8))) u16 u16x8;
typedef __attribute__((ext_vector_type(4))) u16 u16x4;

#define AS1 __attribute__((address_space(1)))
#define AS3 __attribute__((address_space(3)))

__device__ __forceinline__ void gload16(const void* g, void* l) {
  __builtin_amdgcn_global_load_lds((const AS1 void*)g, (AS3 void*)l, 16, 0, 0);
}

__device__ __forceinline__ float bf2f(u16 u) {
  union { uint32_t i; float f; } v; v.i = ((uint32_t)u) << 16; return v.f;
}
__device__ __forceinline__ u16 f2bf(float f) {  // RTNE
  uint32_t x = __builtin_bit_cast(uint32_t, f);
  x += 0x7fffu + ((x >> 16) & 1u);
  return (u16)(x >> 16);
}
__device__ __forceinline__ float phi_f(float x) { return x > 0.f ? x + 1.f : __expf(x); }

__device__ __forceinline__ f32x4 mfma16(bf16x8 a, bf16x8 b, f32x4 c) {
  return __builtin_amdgcn_mfma_f32_16x16x32_bf16(a, b, c, 0, 0, 0);
}

__device__ __forceinline__ int permrow(int r) {
  return (r & ~63) | (((r & 3) << 4) + ((r & 63) >> 2));
}

// ---------------- workspace layout (bytes) — total 249,102,336 ----------------
#define OFF_WQT  0ULL
#define OFF_WKT  (OFF_WQT + 524288ULL)
#define OFF_WVT  (OFF_WKT + 524288ULL)
#define OFF_WOT  (OFF_WVT + 524288ULL)
#define OFF_PQ   (OFF_WOT + 8388608ULL)
#define OFF_PKT  (OFF_PQ  + 67108864ULL)
#define OFF_VT   (OFF_PKT + 67108864ULL)
#define OFF_KVP  (OFF_VT  + 67108864ULL)
#define OFF_KVT  (OFF_KVP + 33554432ULL)
#define OFF_KSUM (OFF_KVT + 4194304ULL)
#define OFF_CTX  OFF_PKT
#define WS_NEED  (OFF_KSUM + 65536ULL)

// ------------- batched square transpose + cvt + 64-group row permute ----------
__global__ __launch_bounds__(256) void mla_transpose_cvt(const float* __restrict__ src,
                                                         u16* __restrict__ dst, int n) {
  __shared__ u16 tile[32][33];
  const int b = blockIdx.z;
  const float* s = src + (size_t)b * n * n;
  u16* d = dst + (size_t)b * n * n;
  const int x = blockIdx.x * 32 + threadIdx.x;
  const int y0 = blockIdx.y * 32 + threadIdx.y;
  #pragma unroll
  for (int i = 0; i < 32; i += 8)
    tile[threadIdx.y + i][threadIdx.x] = f2bf(s[(size_t)(y0 + i) * n + x]);
  __syncthreads();
  const int x2 = blockIdx.y * 32 + threadIdx.x;
  const int y2 = blockIdx.x * 32 + threadIdx.y;
  #pragma unroll
  for (int i = 0; i < 32; i += 8) {
    int pr = permrow(y2 + i);
    d[(size_t)pr * n + x2] = tile[threadIdx.x][threadIdx.y + i];
  }
}

// ---------------- K1: q/k/v projections + phi — T14 W-prefetch (r10) ---------
__global__ __launch_bounds__(256, 2) void mla_qkv(
    const float* __restrict__ X, const u16* __restrict__ WqT,
    const u16* __restrict__ WkT, const u16* __restrict__ WvT,
    u16* __restrict__ pq, u16* __restrict__ pkT, u16* __restrict__ vT) {
  __shared__ u16 ldsX[128 * 128];
  __shared__ u16 ldsW[128 * 128];
  const int t = threadIdx.x;
  const int rt = blockIdx.x, h = blockIdx.y;
  const int r0 = rt * 128;
  const int b = r0 >> 11;
  const int sl0 = r0 & 2047;
  const int bh = b * 16 + h;
  const u16* W0g = WqT + h * 16384;
  const u16* W1g = WkT + h * 16384;
  const u16* W2g = WvT + h * 16384;

  // W0 -> LDS (async), W1/W2 -> registers (plain loads, issued early)
  #pragma unroll
  for (int i = 0; i < 8; ++i)
    gload16(W0g + i * 2048 + t * 8, &ldsW[i * 2048 + t * 8]);
  u16x8 w1r[8], w2r[8];
  #pragma unroll
  for (int i = 0; i < 8; ++i) w1r[i] = *(const u16x8*)(W1g + i * 2048 + t * 8);
  #pragma unroll
  for (int i = 0; i < 8; ++i) w2r[i] = *(const u16x8*)(W2g + i * 2048 + t * 8);

  const float* Xg = X + (size_t)r0 * 2048 + h * 128;
  #pragma unroll
  for (int j = 0; j < 8; ++j) {
    int e = j * 2048 + t * 8;
    int row = e >> 7, col = e & 127;
    const float* p = Xg + (size_t)row * 2048 + col;
    f32x4 a = *(const f32x4*)p;
    f32x4 c = *(const f32x4*)(p + 4);
    u16x8 wv;
    #pragma unroll
    for (int q = 0; q < 4; ++q) { wv[q] = f2bf(a[q]); wv[4 + q] = f2bf(c[q]); }
    *(u16x8*)&ldsX[permrow(row) * 128 + col] = wv;
  }
  __syncthreads();   // X + W0 visible; w1r/w2r landed during X-convert

  const int wave = t >> 6, lane = t & 63;
  const int wm = (wave >> 1) * 64, wn = (wave & 1) * 64;
  const int lr = lane & 15, lk = (lane >> 4) * 8, r4 = (lane >> 4) * 4;
  const int rainv0 = (lr & 3) * 16 + (lr >> 2);

  for (int wsel = 0; wsel < 3; ++wsel) {
    if (wsel) {
      __syncthreads();                     // all waves done reading ldsW
      const u16x8* wsrcr = (wsel == 1) ? w1r : w2r;
      #pragma unroll
      for (int i = 0; i < 8; ++i)
        *(u16x8*)&ldsW[i * 2048 + t * 8] = wsrcr[i];
      __syncthreads();                     // new W visible (reg->LDS)
    }
    f32x4 acc[4][4];
    #pragma unroll
    for (int mb = 0; mb < 4; ++mb)
      #pragma unroll
      for (int nb = 0; nb < 4; ++nb) acc[mb][nb] = (f32x4)0.f;

    if (wsel == 0) {
      #pragma unroll
      for (int ks = 0; ks < 4; ++ks) {
        bf16x8 af[4], bb[4];
        #pragma unroll
        for (int mb = 0; mb < 4; ++mb)
          af[mb] = *(const bf16x8*)&ldsX[(wm + rainv0 + mb * 4) * 128 + ks * 32 + lk];
        #pragma unroll
        for (int nb = 0; nb < 4; ++nb)
          bb[nb] = *(const bf16x8*)&ldsW[(wn + nb * 16 + lr) * 128 + ks * 32 + lk];
        #pragma unroll
        for (int mb = 0; mb < 4; ++mb)
          #pragma unroll
          for (int nb = 0; nb < 4; ++nb)
            acc[mb][nb] = mfma16(af[mb], bb[nb], acc[mb][nb]);
      }
      u16* outq = pq + (size_t)bh * 262144 + (size_t)sl0 * 128;
      #pragma unroll
      for (int mb = 0; mb < 4; ++mb)
        #pragma unroll
        for (int j = 0; j < 4; ++j) {
          int srow = wm + mb * 16 + r4 + j;
          u16x4 o;
          #pragma unroll
          for (int nb = 0; nb < 4; ++nb) o[nb] = f2bf(phi_f(acc[mb][nb][j]));
          *(u16x4*)&outq[srow * 128 + wn + 4 * lr] = o;
        }
    } else {
      #pragma unroll
      for (int ks = 0; ks < 4; ++ks) {
        bf16x8 af[4], bb[4];
        #pragma unroll
        for (int mb = 0; mb < 4; ++mb)
          af[mb] = *(const bf16x8*)&ldsW[(wm + rainv0 + mb * 4) * 128 + ks * 32 + lk];
        #pragma unroll
        for (int nb = 0; nb < 4; ++nb)
          bb[nb] = *(const bf16x8*)&ldsX[(wn + nb * 16 + lr) * 128 + ks * 32 + lk];
        #pragma unroll
        for (int mb = 0; mb < 4; ++mb)
          #pragma unroll
          for (int nb = 0; nb < 4; ++nb)
            acc[mb][nb] = mfma16(af[mb], bb[nb], acc[mb][nb]);
      }
      u16* outT = (wsel == 1 ? pkT : vT) + (size_t)bh * 262144 + sl0;
      #pragma unroll
      for (int mb = 0; mb < 4; ++mb)
        #pragma unroll
        for (int j = 0; j < 4; ++j) {
          int drow = wm + mb * 16 + r4 + j;
          u16x4 o;
          #pragma unroll
          for (int nb = 0; nb < 4; ++nb) {
            float v0 = acc[mb][nb][j];
            if (wsel == 1) v0 = phi_f(v0);
            o[nb] = f2bf(v0);
          }
          *(u16x4*)&outT[(size_t)drow * 2048 + wn + 4 * lr] = o;
        }
    }
  }
}

// ---------------- K2: kv^T partials — ring-4, single-barrier substep ---------
// Barrier #1 removed (proof: stage(u+3) overwrites slot (u-1)&3; all waves'
// slot-(u-1) reads completed before trailing barrier of u-1). vmcnt(8) +
// trailing barrier keep residency guarantee.
__global__ __launch_bounds__(256) void mla_kv(
    const u16* __restrict__ pkT, const u16* __restrict__ vT, float* __restrict__ kvp) {
  __shared__ u16 ldsA[4 * 4096];
  __shared__ u16 ldsB[4 * 4096];
  const int t = threadIdx.x;
  const int bh = blockIdx.x, part = blockIdx.y;
  const int s0 = part * 512;
  const u16* Ag = pkT + (size_t)bh * 262144;
  const u16* Bg = vT + (size_t)bh * 262144;

  const int o0 = t * 16;
  const int row0 = o0 >> 6;
  const int c0 = ((((o0 >> 4) & 3) ^ ((row0 >> 1) & 3)) * 8);

  const int wave = t >> 6, lane = t & 63;
  const int wm = (wave >> 1) * 64, wn = (wave & 1) * 64;
  const int lr = lane & 15, hi = lane >> 4, r4 = (lane >> 4) * 4;

  char* lA = (char*)ldsA;
  char* lB = (char*)ldsB;

#define KV_STAGE(u, slotb) do { const int _sc = s0 + (u) * 32 + c0; \
    gload16(Ag + (size_t)row0 * 2048 + _sc, lA + (slotb) + o0); \
    gload16(Ag + (size_t)(row0 + 64) * 2048 + _sc, lA + (slotb) + o0 + 4096); \
    gload16(Bg + (size_t)row0 * 2048 + _sc, lB + (slotb) + o0); \
    gload16(Bg + (size_t)(row0 + 64) * 2048 + _sc, lB + (slotb) + o0 + 4096); } while (0)

  auto rdA = [&](int slotb, int r) -> bf16x8 {
    int pp = (r << 6) + (hi << 4);
    pp ^= ((r >> 1) & 3) << 4;
    return *(const bf16x8*)(lA + slotb + pp);
  };
  auto rdB = [&](int slotb, int r) -> bf16x8 {
    int pp = (r << 6) + (hi << 4);
    pp ^= ((r >> 1) & 3) << 4;
    return *(const bf16x8*)(lB + slotb + pp);
  };

  f32x4 acc[4][4];
  #pragma unroll
  for (int mb = 0; mb < 4; ++mb)
    #pragma unroll
    for (int nb = 0; nb < 4; ++nb) acc[mb][nb] = (f32x4)0.f;

  KV_STAGE(0, 0); KV_STAGE(1, 8192); KV_STAGE(2, 16384);
  asm volatile("s_waitcnt vmcnt(8)" ::: "memory");
  __builtin_amdgcn_s_barrier();

  bf16x8 af[4], bb[4];
  for (int u = 0; u < 13; ++u) {
    const int sb = (u & 3) * 8192;
    #pragma unroll
    for (int mb = 0; mb < 4; ++mb) af[mb] = rdB(sb, wm + mb * 16 + lr);  // v: m=e
    #pragma unroll
    for (int nb = 0; nb < 4; ++nb) bb[nb] = rdA(sb, wn + nb * 16 + lr);  // pk: n=d
    KV_STAGE(u + 3, ((u + 3) & 3) * 8192);
    __builtin_amdgcn_sched_barrier(0);
    __builtin_amdgcn_s_setprio(1);
    #pragma unroll
    for (int mb = 0; mb < 4; ++mb)
      #pragma unroll
      for (int nb = 0; nb < 4; ++nb)
        acc[mb][nb] = mfma16(af[mb], bb[nb], acc[mb][nb]);
    __builtin_amdgcn_s_setprio(0);
    asm volatile("s_waitcnt vmcnt(8)" ::: "memory");
    __builtin_amdgcn_s_barrier();
  }
  asm volatile("s_waitcnt vmcnt(0)" ::: "memory");
  __builtin_amdgcn_s_barrier();
  #pragma unroll
  for (int u = 13; u < 16; ++u) {
    const int sb = (u & 3) * 8192;
    #pragma unroll
    for (int mb = 0; mb < 4; ++mb) af[mb] = rdB(sb, wm + mb * 16 + lr);
    #pragma unroll
    for (int nb = 0; nb < 4; ++nb) bb[nb] = rdA(sb, wn + nb * 16 + lr);
    #pragma unroll
    for (int mb = 0; mb < 4; ++mb)
      #pragma unroll
      for (int nb = 0; nb < 4; ++nb)
        acc[mb][nb] = mfma16(af[mb], bb[nb], acc[mb][nb]);
  }
#undef KV_STAGE

  float* op = kvp + ((size_t)part * 128 + bh) * 16384;   // [e][d]
  #pragma unroll
  for (int mb = 0; mb < 4; ++mb)
    #pragma unroll
    for (int nb = 0; nb < 4; ++nb)
      #pragma unroll
      for (int j = 0; j < 4; ++j)
        op[(wm + mb * 16 + r4 + j) * 128 + wn + nb * 16 + lr] = acc[mb][nb][j];
}

// -------- K2b+K2c merged: partial-reduce -> kv^T bf16, and ksum --------------
__global__ __launch_bounds__(256) void mla_kvred_ksum(
    const float* __restrict__ kvp, const u16* __restrict__ pkT,
    u16* __restrict__ kvT, float* __restrict__ ksum) {
  const int bid = (int)blockIdx.x;
  const int t = threadIdx.x;
  if (bid < 1024) {
    const size_t i0 = ((size_t)bid * 256 + t) * 8;
    f32x4 lo = (f32x4)0.f, hi = (f32x4)0.f;
    #pragma unroll
    for (int p = 0; p < 4; ++p) {
      const float* src = kvp + (size_t)p * 2097152 + i0;
      lo += *(const f32x4*)src;
      hi += *(const f32x4*)(src + 4);
    }
    u16x8 o;
    #pragma unroll
    for (int j = 0; j < 4; ++j) { o[j] = f2bf(lo[j]); o[4 + j] = f2bf(hi[j]); }
    *(u16x8*)(kvT + i0) = o;
  } else {
    const int lane = t & 63, wave = t >> 6;
    const int gw = (bid - 1024) * 4 + wave;
    const u16* row = pkT + (size_t)gw * 2048;
    float s = 0.f;
    #pragma unroll
    for (int g = 0; g < 4; ++g) {
      u16x8 v = *(const u16x8*)&row[g * 512 + lane * 8];
      #pragma unroll
      for (int j = 0; j < 8; ++j) s += bf2f(v[j]);
    }
    #pragma unroll
    for (int off = 32; off; off >>= 1) s += __shfl_down(s, off);
    if (lane == 0) ksum[gw] = s;
  }
}

// ---------------- K3: num = pq@kv, den = pq@ksum, ctx = num/(den+eps) --------
__global__ __launch_bounds__(256) void mla_ctx(
    const u16* __restrict__ pq, const u16* __restrict__ kvT,
    const float* __restrict__ ksum, u16* __restrict__ ctx) {
  __shared__ u16 ldsA[128 * 128];
  __shared__ float ksl[128];
  __shared__ float dls[128];
  const int t = threadIdx.x;
  const int st = blockIdx.x, bh = blockIdx.y;
  const int sl0 = st * 128;
  const u16* Ag = pq + (size_t)bh * 262144 + (size_t)sl0 * 128;
  const u16* Bg = kvT + (size_t)bh * 16384;
  #pragma unroll
  for (int i = 0; i < 8; ++i)
    gload16(Ag + i * 2048 + t * 8, &ldsA[i * 2048 + t * 8]);
  if (t < 128) ksl[t] = ksum[bh * 128 + t];
  __syncthreads();
  const int wave = t >> 6, lane = t & 63;
  const int wm = (wave >> 1) * 64, wn = (wave & 1) * 64;
  const int lr = lane & 15, lk = (lane >> 4) * 8, r4 = (lane >> 4) * 4;
  f32x4 acc[4][4];
  #pragma unroll
  for (int mb = 0; mb < 4; ++mb)
    #pragma unroll
    for (int nb = 0; nb < 4; ++nb) acc[mb][nb] = (f32x4)0.f;
  #pragma unroll
  for (int ks = 0; ks < 4; ++ks) {
    bf16x8 af[4], bb[4];
    #pragma unroll
    for (int mb = 0; mb < 4; ++mb)
      af[mb] = *(const bf16x8*)&ldsA[(wm + mb * 16 + lr) * 128 + ks * 32 + lk];
    #pragma unroll
    for (int nb = 0; nb < 4; ++nb)
      bb[nb] = *(const bf16x8*)(Bg + (wn + 4 * lr + nb) * 128 + ks * 32 + lk);
    #pragma unroll
    for (int mb = 0; mb < 4; ++mb)
      #pragma unroll
      for (int nb = 0; nb < 4; ++nb)
        acc[mb][nb] = mfma16(af[mb], bb[nb], acc[mb][nb]);
  }
  if (t < 128) {
    float s = 0.f;
    #pragma unroll
    for (int g = 0; g < 16; ++g) {
      int blk = (g + t) & 15;
      u16x8 v = *(const u16x8*)&ldsA[t * 128 + blk * 8];
      #pragma unroll
      for (int j = 0; j < 8; ++j) s += bf2f(v[j]) * ksl[blk * 8 + j];
    }
    dls[t] = s + 1e-6f;
  }
  __syncthreads();
  const int b = bh >> 4, h = bh & 15;
  u16* oc = ctx + ((size_t)b * 2048 + sl0) * 2048 + h * 128;
  #pragma unroll
  for (int mb = 0; mb < 4; ++mb)
    #pragma unroll
    for (int j = 0; j < 4; ++j) {
      int srow = wm + mb * 16 + r4 + j;
      u16x4 o;
      #pragma unroll
      for (int nb = 0; nb < 4; ++nb) o[nb] = f2bf(acc[mb][nb][j] / dls[srow]);
      *(u16x4*)&oc[(size_t)srow * 2048 + wn + 4 * lr] = o;
    }
}

// ---------------- K4: out = ctx @ Wo + bo — single-barrier substep -----------
// r9 merged schedule minus the leading barrier (proof in header comment of
// mla_kv; identical ring-4 / vmcnt(8) argument). Waves may skew within a
// substep -> ds_read traffic overlaps MFMA across waves (1 block/CU).
__global__ __launch_bounds__(512, 2) void mla_out8(
    const u16* __restrict__ ctx, const u16* __restrict__ WoT,
    const float* __restrict__ bo, float* __restrict__ out) {
  __shared__ u16 ldsA[4 * 8192];
  __shared__ u16 ldsB[4 * 8192];
  const int t = threadIdx.x;
  const int bid = (int)blockIdx.x;
  const int swz = (bid & 7) * 64 + (bid >> 3);
  const int mt = swz >> 3, nt = swz & 7;
  const u16* Ag = ctx + (size_t)mt * 256 * 2048;
  const u16* Bg = WoT + (size_t)nt * 256 * 2048;

  const int o0 = t * 16;
  const int row0 = o0 >> 6;
  const int c0 = ((((o0 >> 4) & 3) ^ ((row0 >> 1) & 3)) * 8);

  const int w = t >> 6, lane = t & 63;
  const int wrow = (w >> 2) * 128;
  const int wcol = (w & 3) * 64;
  const int lr = lane & 15, hi = lane >> 4, r4 = (lane >> 4) * 4;

  f32x4 bocache = *(const f32x4*)&bo[nt * 256 + wcol + 4 * lr];

  char* lA = (char*)ldsA;
  char* lB = (char*)ldsB;

#define STAGE_AB(u) do { const int _sl = ((u) & 3) * 16384; \
    gload16(Ag + (size_t)row0 * 2048 + (u) * 32 + c0, lA + _sl + o0); \
    gload16(Ag + (size_t)(row0 + 128) * 2048 + (u) * 32 + c0, lA + _sl + o0 + 8192); \
    gload16(Bg + (size_t)row0 * 2048 + (u) * 32 + c0, lB + _sl + o0); \
    gload16(Bg + (size_t)(row0 + 128) * 2048 + (u) * 32 + c0, lB + _sl + o0 + 8192); } while (0)

  auto rdA = [&](int slotb, int r) -> bf16x8 {
    int p = (r << 6) + (hi << 4);
    p ^= ((r >> 1) & 3) << 4;
    return *(const bf16x8*)(lA + slotb + p);
  };
  auto rdB = [&](int slotb, int r) -> bf16x8 {
    int p = (r << 6) + (hi << 4);
    p ^= ((r >> 1) & 3) << 4;
    return *(const bf16x8*)(lB + slotb + p);
  };

  f32x4 acc0[4][4], acc1[4][4];
  #pragma unroll
  for (int mb = 0; mb < 4; ++mb)
    #pragma unroll
    for (int nb = 0; nb < 4; ++nb) { acc0[mb][nb] = (f32x4)0.f; acc1[mb][nb] = (f32x4)0.f; }

  STAGE_AB(0); STAGE_AB(1); STAGE_AB(2);
  asm volatile("s_waitcnt vmcnt(8)" ::: "memory");
  __builtin_amdgcn_s_barrier();

  bf16x8 af[8], bb[4];

  for (int u = 0; u < 61; ++u) {
    const int sb = (u & 3) * 16384;
    #pragma unroll
    for (int nb = 0; nb < 4; ++nb) bb[nb] = rdB(sb, wcol + nb * 16 + lr);
    #pragma unroll
    for (int mf = 0; mf < 8; ++mf) af[mf] = rdA(sb, wrow + mf * 16 + lr);
    STAGE_AB(u + 3);
    __builtin_amdgcn_sched_barrier(0);
    __builtin_amdgcn_s_setprio(1);
    #pragma unroll
    for (int mb = 0; mb < 4; ++mb)
      #pragma unroll
      for (int nb = 0; nb < 4; ++nb)
        acc0[mb][nb] = mfma16(af[mb], bb[nb], acc0[mb][nb]);
    #pragma unroll
    for (int mb = 0; mb < 4; ++mb)
      #pragma unroll
      for (int nb = 0; nb < 4; ++nb)
        acc1[mb][nb] = mfma16(af[4 + mb], bb[nb], acc1[mb][nb]);
    __builtin_amdgcn_s_setprio(0);
    asm volatile("s_waitcnt vmcnt(8)" ::: "memory");
    __builtin_amdgcn_s_barrier();
  }

  asm volatile("s_waitcnt vmcnt(0)" ::: "memory");
  __builtin_amdgcn_s_barrier();
  #pragma unroll
  for (int u = 61; u < 64; ++u) {
    const int sb = (u & 3) * 16384;
    #pragma unroll
    for (int nb = 0; nb < 4; ++nb) bb[nb] = rdB(sb, wcol + nb * 16 + lr);
    #pragma unroll
    for (int mf = 0; mf < 8; ++mf) af[mf] = rdA(sb, wrow + mf * 16 + lr);
    #pragma unroll
    for (int mb = 0; mb < 4; ++mb)
      #pragma unroll
      for (int nb = 0; nb < 4; ++nb)
        acc0[mb][nb] = mfma16(af[mb], bb[nb], acc0[mb][nb]);
    #pragma unroll
    for (int mb = 0; mb < 4; ++mb)
      #pragma unroll
      for (int nb = 0; nb < 4; ++nb)
        acc1[mb][nb] = mfma16(af[4 + mb], bb[nb], acc1[mb][nb]);
  }
#undef STAGE_AB

  const size_t obase = (size_t)(mt * 256 + wrow) * 2048 + nt * 256 + wcol + 4 * lr;
  #pragma unroll
  for (int mb = 0; mb < 4; ++mb)
    #pragma unroll
    for (int j = 0; j < 4; ++j) {
      f32x4 v0, v1;
      #pragma unroll
      for (int nb = 0; nb < 4; ++nb) {
        v0[nb] = acc0[mb][nb][j] + bocache[nb];
        v1[nb] = acc1[mb][nb][j] + bocache[nb];
      }
      *(f32x4*)&out[obase + (size_t)(mb * 16 + r4 + j) * 2048] = v0;
      *(f32x4*)&out[obase + (size_t)(64 + mb * 16 + r4 + j) * 2048] = v1;
    }
}

extern "C" void kernel_launch(void* const* d_in, const int* in_sizes, int n_in,
                              void* d_out, int out_size, void* d_ws, size_t ws_size,
                              hipStream_t stream) {
  (void)in_sizes; (void)n_in; (void)out_size;
  const float* X  = (const float*)d_in[0];
  const float* Wq = (const float*)d_in[1];
  const float* Wk = (const float*)d_in[2];
  const float* Wv = (const float*)d_in[3];
  const float* Wo = (const float*)d_in[4];
  const float* bo = (const float*)d_in[5];
  float* out = (float*)d_out;
  char* ws = (char*)d_ws;
  if (ws_size < WS_NEED) return;

  u16*   wqT  = (u16*)(ws + OFF_WQT);
  u16*   wkT  = (u16*)(ws + OFF_WKT);
  u16*   wvT  = (u16*)(ws + OFF_WVT);
  u16*   woT  = (u16*)(ws + OFF_WOT);
  u16*   pq   = (u16*)(ws + OFF_PQ);
  u16*   pkT  = (u16*)(ws + OFF_PKT);
  u16*   vT   = (u16*)(ws + OFF_VT);
  float* kvp  = (float*)(ws + OFF_KVP);
  u16*   kvT  = (u16*)(ws + OFF_KVT);
  float* ksum = (float*)(ws + OFF_KSUM);
  u16*   ctx  = (u16*)(ws + OFF_CTX);

  dim3 tb(32, 8);
  mla_transpose_cvt<<<dim3(4, 4, 16), tb, 0, stream>>>(Wq, wqT, 128);
  mla_transpose_cvt<<<dim3(4, 4, 16), tb, 0, stream>>>(Wk, wkT, 128);
  mla_transpose_cvt<<<dim3(4, 4, 16), tb, 0, stream>>>(Wv, wvT, 128);
  mla_transpose_cvt<<<dim3(64, 64, 1), tb, 0, stream>>>(Wo, woT, 2048);
  mla_qkv<<<dim3(128, 16), 256, 0, stream>>>(X, wqT, wkT, wvT, pq, pkT, vT);
  mla_kv<<<dim3(128, 4), 256, 0, stream>>>(pkT, vT, kvp);
  mla_kvred_ksum<<<5120, 256, 0, stream>>>(kvp, pkT, kvT, ksum);
  mla_ctx<<<dim3(16, 128), 256, 0, stream>>>(pq, kvT, ksum, ctx);
  mla_out8<<<512, 512, 0, stream>>>(ctx, woT, bo, out);
}

// Round 15
// 337.753 us; speedup vs baseline: 5.0787x; 1.0182x over previous
//
#include <hip/hip_runtime.h>
#include <stdint.h>

typedef unsigned short u16;
typedef __attribute__((ext_vector_type(4))) float f32x4;
typedef __attribute__((ext_vector_type(8))) __bf16 bf16x8;
typedef __attribute__((ext_vector_type(8))) u16 u16x8;
typedef __attribute__((ext_vector_type(4))) u16 u16x4;

#define AS1 __attribute__((address_space(1)))
#define AS3 __attribute__((address_space(3)))

__device__ __forceinline__ void gload16(const void* g, void* l) {
  __builtin_amdgcn_global_load_lds((const AS1 void*)g, (AS3 void*)l, 16, 0, 0);
}

__device__ __forceinline__ float bf2f(u16 u) {
  union { uint32_t i; float f; } v; v.i = ((uint32_t)u) << 16; return v.f;
}
__device__ __forceinline__ u16 f2bf(float f) {  // RTNE
  uint32_t x = __builtin_bit_cast(uint32_t, f);
  x += 0x7fffu + ((x >> 16) & 1u);
  return (u16)(x >> 16);
}
__device__ __forceinline__ float phi_f(float x) { return x > 0.f ? x + 1.f : __expf(x); }

__device__ __forceinline__ f32x4 mfma16(bf16x8 a, bf16x8 b, f32x4 c) {
  return __builtin_amdgcn_mfma_f32_16x16x32_bf16(a, b, c, 0, 0, 0);
}

__device__ __forceinline__ int permrow(int r) {
  return (r & ~63) | (((r & 3) << 4) + ((r & 63) >> 2));
}

// ---------------- workspace layout (bytes) ----------------
#define OFF_WQT  0ULL
#define OFF_WKT  (OFF_WQT + 524288ULL)
#define OFF_WVT  (OFF_WKT + 524288ULL)
#define OFF_WOT  (OFF_WVT + 524288ULL)
#define OFF_PQ   (OFF_WOT + 8388608ULL)
#define OFF_PKT  (OFF_PQ  + 67108864ULL)
#define OFF_VT   (OFF_PKT + 67108864ULL)
#define OFF_KVP  (OFF_VT  + 67108864ULL)          // [2 part][128 bh][16384] f32
#define OFF_KVT  (OFF_KVP + 33554432ULL)
#define OFF_KSUM (OFF_KVT + 4194304ULL)
#define OFF_CTX  OFF_PKT
#define WS_NEED  (OFF_KSUM + 65536ULL)

// ------------- Wo transpose + cvt + 64-group row permute ----------------
__global__ __launch_bounds__(256) void mla_transpose_cvt(const float* __restrict__ src,
                                                         u16* __restrict__ dst, int n) {
  __shared__ u16 tile[32][33];
  const int b = blockIdx.z;
  const float* s = src + (size_t)b * n * n;
  u16* d = dst + (size_t)b * n * n;
  const int x = blockIdx.x * 32 + threadIdx.x;
  const int y0 = blockIdx.y * 32 + threadIdx.y;
  #pragma unroll
  for (int i = 0; i < 32; i += 8)
    tile[threadIdx.y + i][threadIdx.x] = f2bf(s[(size_t)(y0 + i) * n + x]);
  __syncthreads();
  const int x2 = blockIdx.y * 32 + threadIdx.x;
  const int y2 = blockIdx.x * 32 + threadIdx.y;
  #pragma unroll
  for (int i = 0; i < 32; i += 8) {
    int pr = permrow(y2 + i);
    d[(size_t)pr * n + x2] = tile[threadIdx.x][threadIdx.y + i];
  }
}

// ------------- fused Wq/Wk/Wv transpose (n=128, z = 16 heads x 3 mats) -------
__global__ __launch_bounds__(256) void mla_transpose_qkvw(
    const float* __restrict__ Wq, const float* __restrict__ Wk,
    const float* __restrict__ Wv, u16* __restrict__ wqT,
    u16* __restrict__ wkT, u16* __restrict__ wvT) {
  __shared__ u16 tile[32][33];
  const int z = blockIdx.z;
  const int m = z / 16, b = z % 16;               // matrix, head
  const float* s = (m == 0 ? Wq : m == 1 ? Wk : Wv) + (size_t)b * 16384;
  u16* d = (m == 0 ? wqT : m == 1 ? wkT : wvT) + (size_t)b * 16384;
  const int x = blockIdx.x * 32 + threadIdx.x;
  const int y0 = blockIdx.y * 32 + threadIdx.y;
  #pragma unroll
  for (int i = 0; i < 32; i += 8)
    tile[threadIdx.y + i][threadIdx.x] = f2bf(s[(size_t)(y0 + i) * 128 + x]);
  __syncthreads();
  const int x2 = blockIdx.y * 32 + threadIdx.x;
  const int y2 = blockIdx.x * 32 + threadIdx.y;
  #pragma unroll
  for (int i = 0; i < 32; i += 8) {
    int pr = permrow(y2 + i);
    d[(size_t)pr * 128 + x2] = tile[threadIdx.x][threadIdx.y + i];
  }
}

// ---------------- K1: q/k/v projections + phi — T14 W-prefetch (r10) ---------
__global__ __launch_bounds__(256, 2) void mla_qkv(
    const float* __restrict__ X, const u16* __restrict__ WqT,
    const u16* __restrict__ WkT, const u16* __restrict__ WvT,
    u16* __restrict__ pq, u16* __restrict__ pkT, u16* __restrict__ vT) {
  __shared__ u16 ldsX[128 * 128];
  __shared__ u16 ldsW[128 * 128];
  const int t = threadIdx.x;
  const int rt = blockIdx.x, h = blockIdx.y;
  const int r0 = rt * 128;
  const int b = r0 >> 11;
  const int sl0 = r0 & 2047;
  const int bh = b * 16 + h;
  const u16* W0g = WqT + h * 16384;
  const u16* W1g = WkT + h * 16384;
  const u16* W2g = WvT + h * 16384;

  #pragma unroll
  for (int i = 0; i < 8; ++i)
    gload16(W0g + i * 2048 + t * 8, &ldsW[i * 2048 + t * 8]);
  u16x8 w1r[8], w2r[8];
  #pragma unroll
  for (int i = 0; i < 8; ++i) w1r[i] = *(const u16x8*)(W1g + i * 2048 + t * 8);
  #pragma unroll
  for (int i = 0; i < 8; ++i) w2r[i] = *(const u16x8*)(W2g + i * 2048 + t * 8);

  const float* Xg = X + (size_t)r0 * 2048 + h * 128;
  #pragma unroll
  for (int j = 0; j < 8; ++j) {
    int e = j * 2048 + t * 8;
    int row = e >> 7, col = e & 127;
    const float* p = Xg + (size_t)row * 2048 + col;
    f32x4 a = *(const f32x4*)p;
    f32x4 c = *(const f32x4*)(p + 4);
    u16x8 wv;
    #pragma unroll
    for (int q = 0; q < 4; ++q) { wv[q] = f2bf(a[q]); wv[4 + q] = f2bf(c[q]); }
    *(u16x8*)&ldsX[permrow(row) * 128 + col] = wv;
  }
  __syncthreads();

  const int wave = t >> 6, lane = t & 63;
  const int wm = (wave >> 1) * 64, wn = (wave & 1) * 64;
  const int lr = lane & 15, lk = (lane >> 4) * 8, r4 = (lane >> 4) * 4;
  const int rainv0 = (lr & 3) * 16 + (lr >> 2);

  for (int wsel = 0; wsel < 3; ++wsel) {
    if (wsel) {
      __syncthreads();
      const u16x8* wsrcr = (wsel == 1) ? w1r : w2r;
      #pragma unroll
      for (int i = 0; i < 8; ++i)
        *(u16x8*)&ldsW[i * 2048 + t * 8] = wsrcr[i];
      __syncthreads();
    }
    f32x4 acc[4][4];
    #pragma unroll
    for (int mb = 0; mb < 4; ++mb)
      #pragma unroll
      for (int nb = 0; nb < 4; ++nb) acc[mb][nb] = (f32x4)0.f;

    if (wsel == 0) {
      #pragma unroll
      for (int ks = 0; ks < 4; ++ks) {
        bf16x8 af[4], bb[4];
        #pragma unroll
        for (int mb = 0; mb < 4; ++mb)
          af[mb] = *(const bf16x8*)&ldsX[(wm + rainv0 + mb * 4) * 128 + ks * 32 + lk];
        #pragma unroll
        for (int nb = 0; nb < 4; ++nb)
          bb[nb] = *(const bf16x8*)&ldsW[(wn + nb * 16 + lr) * 128 + ks * 32 + lk];
        #pragma unroll
        for (int mb = 0; mb < 4; ++mb)
          #pragma unroll
          for (int nb = 0; nb < 4; ++nb)
            acc[mb][nb] = mfma16(af[mb], bb[nb], acc[mb][nb]);
      }
      u16* outq = pq + (size_t)bh * 262144 + (size_t)sl0 * 128;
      #pragma unroll
      for (int mb = 0; mb < 4; ++mb)
        #pragma unroll
        for (int j = 0; j < 4; ++j) {
          int srow = wm + mb * 16 + r4 + j;
          u16x4 o;
          #pragma unroll
          for (int nb = 0; nb < 4; ++nb) o[nb] = f2bf(phi_f(acc[mb][nb][j]));
          *(u16x4*)&outq[srow * 128 + wn + 4 * lr] = o;
        }
    } else {
      #pragma unroll
      for (int ks = 0; ks < 4; ++ks) {
        bf16x8 af[4], bb[4];
        #pragma unroll
        for (int mb = 0; mb < 4; ++mb)
          af[mb] = *(const bf16x8*)&ldsW[(wm + rainv0 + mb * 4) * 128 + ks * 32 + lk];
        #pragma unroll
        for (int nb = 0; nb < 4; ++nb)
          bb[nb] = *(const bf16x8*)&ldsX[(wn + nb * 16 + lr) * 128 + ks * 32 + lk];
        #pragma unroll
        for (int mb = 0; mb < 4; ++mb)
          #pragma unroll
          for (int nb = 0; nb < 4; ++nb)
            acc[mb][nb] = mfma16(af[mb], bb[nb], acc[mb][nb]);
      }
      u16* outT = (wsel == 1 ? pkT : vT) + (size_t)bh * 262144 + sl0;
      #pragma unroll
      for (int mb = 0; mb < 4; ++mb)
        #pragma unroll
        for (int j = 0; j < 4; ++j) {
          int drow = wm + mb * 16 + r4 + j;
          u16x4 o;
          #pragma unroll
          for (int nb = 0; nb < 4; ++nb) {
            float v0 = acc[mb][nb][j];
            if (wsel == 1) v0 = phi_f(v0);
            o[nb] = f2bf(v0);
          }
          *(u16x4*)&outT[(size_t)drow * 2048 + wn + 4 * lr] = o;
        }
    }
  }
}

// ---------------- K2: kv^T partials — ring-4, single-barrier, 2 partitions ---
// part in {0,1}; 256 blocks = 1/CU; 32 substeps each; half the partial traffic.
__global__ __launch_bounds__(256) void mla_kv(
    const u16* __restrict__ pkT, const u16* __restrict__ vT, float* __restrict__ kvp) {
  __shared__ u16 ldsA[4 * 4096];
  __shared__ u16 ldsB[4 * 4096];
  const int t = threadIdx.x;
  const int bh = blockIdx.x, part = blockIdx.y;
  const int s0 = part * 1024;
  const u16* Ag = pkT + (size_t)bh * 262144;
  const u16* Bg = vT + (size_t)bh * 262144;

  const int o0 = t * 16;
  const int row0 = o0 >> 6;
  const int c0 = ((((o0 >> 4) & 3) ^ ((row0 >> 1) & 3)) * 8);

  const int wave = t >> 6, lane = t & 63;
  const int wm = (wave >> 1) * 64, wn = (wave & 1) * 64;
  const int lr = lane & 15, hi = lane >> 4, r4 = (lane >> 4) * 4;

  char* lA = (char*)ldsA;
  char* lB = (char*)ldsB;

#define KV_STAGE(u, slotb) do { const int _sc = s0 + (u) * 32 + c0; \
    gload16(Ag + (size_t)row0 * 2048 + _sc, lA + (slotb) + o0); \
    gload16(Ag + (size_t)(row0 + 64) * 2048 + _sc, lA + (slotb) + o0 + 4096); \
    gload16(Bg + (size_t)row0 * 2048 + _sc, lB + (slotb) + o0); \
    gload16(Bg + (size_t)(row0 + 64) * 2048 + _sc, lB + (slotb) + o0 + 4096); } while (0)

  auto rdA = [&](int slotb, int r) -> bf16x8 {
    int pp = (r << 6) + (hi << 4);
    pp ^= ((r >> 1) & 3) << 4;
    return *(const bf16x8*)(lA + slotb + pp);
  };
  auto rdB = [&](int slotb, int r) -> bf16x8 {
    int pp = (r << 6) + (hi << 4);
    pp ^= ((r >> 1) & 3) << 4;
    return *(const bf16x8*)(lB + slotb + pp);
  };

  f32x4 acc[4][4];
  #pragma unroll
  for (int mb = 0; mb < 4; ++mb)
    #pragma unroll
    for (int nb = 0; nb < 4; ++nb) acc[mb][nb] = (f32x4)0.f;

  KV_STAGE(0, 0); KV_STAGE(1, 8192); KV_STAGE(2, 16384);
  asm volatile("s_waitcnt vmcnt(8)" ::: "memory");
  __builtin_amdgcn_s_barrier();

  bf16x8 af[4], bb[4];
  for (int u = 0; u < 29; ++u) {
    const int sb = (u & 3) * 8192;
    #pragma unroll
    for (int mb = 0; mb < 4; ++mb) af[mb] = rdB(sb, wm + mb * 16 + lr);  // v: m=e
    #pragma unroll
    for (int nb = 0; nb < 4; ++nb) bb[nb] = rdA(sb, wn + nb * 16 + lr);  // pk: n=d
    KV_STAGE(u + 3, ((u + 3) & 3) * 8192);
    __builtin_amdgcn_sched_barrier(0);
    __builtin_amdgcn_s_setprio(1);
    #pragma unroll
    for (int mb = 0; mb < 4; ++mb)
      #pragma unroll
      for (int nb = 0; nb < 4; ++nb)
        acc[mb][nb] = mfma16(af[mb], bb[nb], acc[mb][nb]);
    __builtin_amdgcn_s_setprio(0);
    asm volatile("s_waitcnt vmcnt(8)" ::: "memory");
    __builtin_amdgcn_s_barrier();
  }
  asm volatile("s_waitcnt vmcnt(0)" ::: "memory");
  __builtin_amdgcn_s_barrier();
  #pragma unroll
  for (int u = 29; u < 32; ++u) {
    const int sb = (u & 3) * 8192;
    #pragma unroll
    for (int mb = 0; mb < 4; ++mb) af[mb] = rdB(sb, wm + mb * 16 + lr);
    #pragma unroll
    for (int nb = 0; nb < 4; ++nb) bb[nb] = rdA(sb, wn + nb * 16 + lr);
    #pragma unroll
    for (int mb = 0; mb < 4; ++mb)
      #pragma unroll
      for (int nb = 0; nb < 4; ++nb)
        acc[mb][nb] = mfma16(af[mb], bb[nb], acc[mb][nb]);
  }
#undef KV_STAGE

  float* op = kvp + ((size_t)part * 128 + bh) * 16384;   // [e][d]
  #pragma unroll
  for (int mb = 0; mb < 4; ++mb)
    #pragma unroll
    for (int nb = 0; nb < 4; ++nb)
      #pragma unroll
      for (int j = 0; j < 4; ++j)
        op[(wm + mb * 16 + r4 + j) * 128 + wn + nb * 16 + lr] = acc[mb][nb][j];
}

// -------- K2b+K2c merged: 2-partial reduce -> kv^T bf16, and ksum ------------
__global__ __launch_bounds__(256) void mla_kvred_ksum(
    const float* __restrict__ kvp, const u16* __restrict__ pkT,
    u16* __restrict__ kvT, float* __restrict__ ksum) {
  const int bid = (int)blockIdx.x;
  const int t = threadIdx.x;
  if (bid < 1024) {
    const size_t i0 = ((size_t)bid * 256 + t) * 8;
    f32x4 lo = (f32x4)0.f, hi = (f32x4)0.f;
    #pragma unroll
    for (int p = 0; p < 2; ++p) {
      const float* src = kvp + (size_t)p * 2097152 + i0;
      lo += *(const f32x4*)src;
      hi += *(const f32x4*)(src + 4);
    }
    u16x8 o;
    #pragma unroll
    for (int j = 0; j < 4; ++j) { o[j] = f2bf(lo[j]); o[4 + j] = f2bf(hi[j]); }
    *(u16x8*)(kvT + i0) = o;
  } else {
    const int lane = t & 63, wave = t >> 6;
    const int gw = (bid - 1024) * 4 + wave;
    const u16* row = pkT + (size_t)gw * 2048;
    float s = 0.f;
    #pragma unroll
    for (int g = 0; g < 4; ++g) {
      u16x8 v = *(const u16x8*)&row[g * 512 + lane * 8];
      #pragma unroll
      for (int j = 0; j < 8; ++j) s += bf2f(v[j]);
    }
    #pragma unroll
    for (int off = 32; off; off >>= 1) s += __shfl_down(s, off);
    if (lane == 0) ksum[gw] = s;
  }
}

// ---------------- K3: num = pq@kv, den = pq@ksum, ctx = num/(den+eps) --------
__global__ __launch_bounds__(256) void mla_ctx(
    const u16* __restrict__ pq, const u16* __restrict__ kvT,
    const float* __restrict__ ksum, u16* __restrict__ ctx) {
  __shared__ u16 ldsA[128 * 128];
  __shared__ float ksl[128];
  __shared__ float dls[128];
  const int t = threadIdx.x;
  const int st = blockIdx.x, bh = blockIdx.y;
  const int sl0 = st * 128;
  const u16* Ag = pq + (size_t)bh * 262144 + (size_t)sl0 * 128;
  const u16* Bg = kvT + (size_t)bh * 16384;
  #pragma unroll
  for (int i = 0; i < 8; ++i)
    gload16(Ag + i * 2048 + t * 8, &ldsA[i * 2048 + t * 8]);
  if (t < 128) ksl[t] = ksum[bh * 128 + t];
  __syncthreads();
  const int wave = t >> 6, lane = t & 63;
  const int wm = (wave >> 1) * 64, wn = (wave & 1) * 64;
  const int lr = lane & 15, lk = (lane >> 4) * 8, r4 = (lane >> 4) * 4;
  f32x4 acc[4][4];
  #pragma unroll
  for (int mb = 0; mb < 4; ++mb)
    #pragma unroll
    for (int nb = 0; nb < 4; ++nb) acc[mb][nb] = (f32x4)0.f;
  #pragma unroll
  for (int ks = 0; ks < 4; ++ks) {
    bf16x8 af[4], bb[4];
    #pragma unroll
    for (int mb = 0; mb < 4; ++mb)
      af[mb] = *(const bf16x8*)&ldsA[(wm + mb * 16 + lr) * 128 + ks * 32 + lk];
    #pragma unroll
    for (int nb = 0; nb < 4; ++nb)
      bb[nb] = *(const bf16x8*)(Bg + (wn + 4 * lr + nb) * 128 + ks * 32 + lk);
    #pragma unroll
    for (int mb = 0; mb < 4; ++mb)
      #pragma unroll
      for (int nb = 0; nb < 4; ++nb)
        acc[mb][nb] = mfma16(af[mb], bb[nb], acc[mb][nb]);
  }
  if (t < 128) {
    float s = 0.f;
    #pragma unroll
    for (int g = 0; g < 16; ++g) {
      int blk = (g + t) & 15;
      u16x8 v = *(const u16x8*)&ldsA[t * 128 + blk * 8];
      #pragma unroll
      for (int j = 0; j < 8; ++j) s += bf2f(v[j]) * ksl[blk * 8 + j];
    }
    dls[t] = s + 1e-6f;
  }
  __syncthreads();
  const int b = bh >> 4, h = bh & 15;
  u16* oc = ctx + ((size_t)b * 2048 + sl0) * 2048 + h * 128;
  #pragma unroll
  for (int mb = 0; mb < 4; ++mb)
    #pragma unroll
    for (int j = 0; j < 4; ++j) {
      int srow = wm + mb * 16 + r4 + j;
      u16x4 o;
      #pragma unroll
      for (int nb = 0; nb < 4; ++nb) o[nb] = f2bf(acc[mb][nb][j] / dls[srow]);
      *(u16x4*)&oc[(size_t)srow * 2048 + wn + 4 * lr] = o;
    }
}

// ---------------- K4: out = ctx @ Wo + bo — single-barrier substep (r14) -----
__global__ __launch_bounds__(512, 2) void mla_out8(
    const u16* __restrict__ ctx, const u16* __restrict__ WoT,
    const float* __restrict__ bo, float* __restrict__ out) {
  __shared__ u16 ldsA[4 * 8192];
  __shared__ u16 ldsB[4 * 8192];
  const int t = threadIdx.x;
  const int bid = (int)blockIdx.x;
  const int swz = (bid & 7) * 64 + (bid >> 3);
  const int mt = swz >> 3, nt = swz & 7;
  const u16* Ag = ctx + (size_t)mt * 256 * 2048;
  const u16* Bg = WoT + (size_t)nt * 256 * 2048;

  const int o0 = t * 16;
  const int row0 = o0 >> 6;
  const int c0 = ((((o0 >> 4) & 3) ^ ((row0 >> 1) & 3)) * 8);

  const int w = t >> 6, lane = t & 63;
  const int wrow = (w >> 2) * 128;
  const int wcol = (w & 3) * 64;
  const int lr = lane & 15, hi = lane >> 4, r4 = (lane >> 4) * 4;

  f32x4 bocache = *(const f32x4*)&bo[nt * 256 + wcol + 4 * lr];

  char* lA = (char*)ldsA;
  char* lB = (char*)ldsB;

#define STAGE_AB(u) do { const int _sl = ((u) & 3) * 16384; \
    gload16(Ag + (size_t)row0 * 2048 + (u) * 32 + c0, lA + _sl + o0); \
    gload16(Ag + (size_t)(row0 + 128) * 2048 + (u) * 32 + c0, lA + _sl + o0 + 8192); \
    gload16(Bg + (size_t)row0 * 2048 + (u) * 32 + c0, lB + _sl + o0); \
    gload16(Bg + (size_t)(row0 + 128) * 2048 + (u) * 32 + c0, lB + _sl + o0 + 8192); } while (0)

  auto rdA = [&](int slotb, int r) -> bf16x8 {
    int p = (r << 6) + (hi << 4);
    p ^= ((r >> 1) & 3) << 4;
    return *(const bf16x8*)(lA + slotb + p);
  };
  auto rdB = [&](int slotb, int r) -> bf16x8 {
    int p = (r << 6) + (hi << 4);
    p ^= ((r >> 1) & 3) << 4;
    return *(const bf16x8*)(lB + slotb + p);
  };

  f32x4 acc0[4][4], acc1[4][4];
  #pragma unroll
  for (int mb = 0; mb < 4; ++mb)
    #pragma unroll
    for (int nb = 0; nb < 4; ++nb) { acc0[mb][nb] = (f32x4)0.f; acc1[mb][nb] = (f32x4)0.f; }

  STAGE_AB(0); STAGE_AB(1); STAGE_AB(2);
  asm volatile("s_waitcnt vmcnt(8)" ::: "memory");
  __builtin_amdgcn_s_barrier();

  bf16x8 af[8], bb[4];

  for (int u = 0; u < 61; ++u) {
    const int sb = (u & 3) * 16384;
    #pragma unroll
    for (int nb = 0; nb < 4; ++nb) bb[nb] = rdB(sb, wcol + nb * 16 + lr);
    #pragma unroll
    for (int mf = 0; mf < 8; ++mf) af[mf] = rdA(sb, wrow + mf * 16 + lr);
    STAGE_AB(u + 3);
    __builtin_amdgcn_sched_barrier(0);
    __builtin_amdgcn_s_setprio(1);
    #pragma unroll
    for (int mb = 0; mb < 4; ++mb)
      #pragma unroll
      for (int nb = 0; nb < 4; ++nb)
        acc0[mb][nb] = mfma16(af[mb], bb[nb], acc0[mb][nb]);
    #pragma unroll
    for (int mb = 0; mb < 4; ++mb)
      #pragma unroll
      for (int nb = 0; nb < 4; ++nb)
        acc1[mb][nb] = mfma16(af[4 + mb], bb[nb], acc1[mb][nb]);
    __builtin_amdgcn_s_setprio(0);
    asm volatile("s_waitcnt vmcnt(8)" ::: "memory");
    __builtin_amdgcn_s_barrier();
  }

  asm volatile("s_waitcnt vmcnt(0)" ::: "memory");
  __builtin_amdgcn_s_barrier();
  #pragma unroll
  for (int u = 61; u < 64; ++u) {
    const int sb = (u & 3) * 16384;
    #pragma unroll
    for (int nb = 0; nb < 4; ++nb) bb[nb] = rdB(sb, wcol + nb * 16 + lr);
    #pragma unroll
    for (int mf = 0; mf < 8; ++mf) af[mf] = rdA(sb, wrow + mf * 16 + lr);
    #pragma unroll
    for (int mb = 0; mb < 4; ++mb)
      #pragma unroll
      for (int nb = 0; nb < 4; ++nb)
        acc0[mb][nb] = mfma16(af[mb], bb[nb], acc0[mb][nb]);
    #pragma unroll
    for (int mb = 0; mb < 4; ++mb)
      #pragma unroll
      for (int nb = 0; nb < 4; ++nb)
        acc1[mb][nb] = mfma16(af[4 + mb], bb[nb], acc1[mb][nb]);
  }
#undef STAGE_AB

  const size_t obase = (size_t)(mt * 256 + wrow) * 2048 + nt * 256 + wcol + 4 * lr;
  #pragma unroll
  for (int mb = 0; mb < 4; ++mb)
    #pragma unroll
    for (int j = 0; j < 4; ++j) {
      f32x4 v0, v1;
      #pragma unroll
      for (int nb = 0; nb < 4; ++nb) {
        v0[nb] = acc0[mb][nb][j] + bocache[nb];
        v1[nb] = acc1[mb][nb][j] + bocache[nb];
      }
      *(f32x4*)&out[obase + (size_t)(mb * 16 + r4 + j) * 2048] = v0;
      *(f32x4*)&out[obase + (size_t)(64 + mb * 16 + r4 + j) * 2048] = v1;
    }
}

extern "C" void kernel_launch(void* const* d_in, const int* in_sizes, int n_in,
                              void* d_out, int out_size, void* d_ws, size_t ws_size,
                              hipStream_t stream) {
  (void)in_sizes; (void)n_in; (void)out_size;
  const float* X  = (const float*)d_in[0];
  const float* Wq = (const float*)d_in[1];
  const float* Wk = (const float*)d_in[2];
  const float* Wv = (const float*)d_in[3];
  const float* Wo = (const float*)d_in[4];
  const float* bo = (const float*)d_in[5];
  float* out = (float*)d_out;
  char* ws = (char*)d_ws;
  if (ws_size < WS_NEED) return;

  u16*   wqT  = (u16*)(ws + OFF_WQT);
  u16*   wkT  = (u16*)(ws + OFF_WKT);
  u16*   wvT  = (u16*)(ws + OFF_WVT);
  u16*   woT  = (u16*)(ws + OFF_WOT);
  u16*   pq   = (u16*)(ws + OFF_PQ);
  u16*   pkT  = (u16*)(ws + OFF_PKT);
  u16*   vT   = (u16*)(ws + OFF_VT);
  float* kvp  = (float*)(ws + OFF_KVP);
  u16*   kvT  = (u16*)(ws + OFF_KVT);
  float* ksum = (float*)(ws + OFF_KSUM);
  u16*   ctx  = (u16*)(ws + OFF_CTX);

  dim3 tb(32, 8);
  mla_transpose_qkvw<<<dim3(4, 4, 48), tb, 0, stream>>>(Wq, Wk, Wv, wqT, wkT, wvT);
  mla_transpose_cvt<<<dim3(64, 64, 1), tb, 0, stream>>>(Wo, woT, 2048);
  mla_qkv<<<dim3(128, 16), 256, 0, stream>>>(X, wqT, wkT, wvT, pq, pkT, vT);
  mla_kv<<<dim3(128, 2), 256, 0, stream>>>(pkT, vT, kvp);
  mla_kvred_ksum<<<5120, 256, 0, stream>>>(kvp, pkT, kvT, ksum);
  mla_ctx<<<dim3(16, 128), 256, 0, stream>>>(pq, kvT, ksum, ctx);
  mla_out8<<<512, 512, 0, stream>>>(ctx, woT, bo, out);
}